// Round 6
// baseline (1778.348 us; speedup 1.0000x reference)
//
#include <hip/hip_runtime.h>

// B=32, S=128, D=300 (pad 320), VOCAB=20000 (625 chunks of 32), K=8.
// Inputs may be f32 or bf16 (runtime-detected); canonicalized to bf16 in ws.

typedef unsigned short u16;
typedef unsigned int   u32;
typedef float  f32x4 __attribute__((ext_vector_type(4)));
typedef u32    u32x4 __attribute__((ext_vector_type(4)));
typedef __bf16 bf16x8 __attribute__((ext_vector_type(8)));
typedef _Float16 f16x8 __attribute__((ext_vector_type(8)));

#define SCOPE_AGENT __HIP_MEMORY_SCOPE_AGENT
#define HSENT 0x7FFF7FFFu

__device__ __forceinline__ float bf2f(u16 u) { return __uint_as_float(((u32)u) << 16); }
__device__ __forceinline__ u16 f2bf(float f) {
  u32 x = __float_as_uint(f);
  u32 r = (x + 0x7fffu + ((x >> 16) & 1u)) >> 16;  // RNE
  return (u16)r;
}
__device__ __forceinline__ u16 f2h(float f) {
  union { _Float16 h; u16 u; } cv; cv.h = (_Float16)f; return cv.u;
}
__device__ __forceinline__ float h2f(u16 u) {
  union { _Float16 h; u16 u; } cv; cv.u = u; return (float)cv.h;
}
__device__ __forceinline__ float sigm_fast(float x) {
  return __builtin_amdgcn_rcpf(1.f + __expf(-x));
}
__device__ __forceinline__ float tanh_fast(float x) {
  return 1.f - 2.f * __builtin_amdgcn_rcpf(1.f + __expf(2.f * x));
}

// quad_perm DPP move (4-lane group permutation, VALU-only cross-lane)
template <int CTRL>
__device__ __forceinline__ float dppq(float v) {
  return __uint_as_float(
      (u32)__builtin_amdgcn_mov_dpp((int)__float_as_uint(v), CTRL, 0xF, 0xF, true));
}

__device__ __forceinline__ f32x4 shflx4(f32x4 v, int m) {
  f32x4 r;
  r[0] = __shfl_xor(v[0], m, 16);
  r[1] = __shfl_xor(v[1], m, 16);
  r[2] = __shfl_xor(v[2], m, 16);
  r[3] = __shfl_xor(v[3], m, 16);
  return r;
}

// ---------- ingest: detect f32 vs bf16, canonicalize all float inputs to bf16 ----------
__device__ __forceinline__ void conv_seg(const void* src, u16* dst, int n, int is32,
                                         int t0, int stride) {
  if (is32) {
    const float* s = (const float*)src;
    for (int i = t0; i < n; i += stride) dst[i] = f2bf(s[i]);
  } else {
    const u16* s = (const u16*)src;
    for (int i = t0; i < n; i += stride) dst[i] = s[i];
  }
}

__global__ __launch_bounds__(256) void k_ingest(
    const void* words, const void* vocab, const void* de, const void* W,
    const void* lWih, const void* lWhh, const void* lbih, const void* lbhh,
    const void* rWih, const void* rWhh, const void* rbih, const void* rbhh,
    u16* cw, u16* cv, u16* cde, u16* cW, u16* cWih, u16* cWhh, u16* cbih, u16* cbhh,
    u16* crWih, u16* crWhh, u16* crbih, u16* crbhh, u32* flag, u32* hbz) {
  __shared__ int s_is32;
  int tid = threadIdx.x;
  int vote = 0;
  if (tid < 64) {
    u32 w = ((const u32*)words)[tid];
    int e = (w >> 7) & 0xFF;  // bf16 low-element exponent field if bf16-packed
    vote = (e >= 100 && e <= 150) ? 1 : 0;
  }
  unsigned long long m = __ballot(vote);
  if (tid == 0) s_is32 = (__popcll(m) < 32) ? 1 : 0;  // few plausible bf16 exps -> f32
  __syncthreads();
  int is32 = s_is32;
  if (blockIdx.x == 0 && tid == 0) *flag = (u32)is32;
  int t0 = blockIdx.x * 256 + tid;
  int stride = gridDim.x * 256;
  // LSTM h dataflow buffers: 129 steps x 5120 u32. Buffer 0 = h_0 = 0.
  // Buffers 1..128 = sentinel, except k-dims >= 300 (never produced) = 0.
  for (int i = t0; i < 660480; i += stride) {
    int tb = i / 5120;
    u32 v = 0u;
    if (tb != 0) {
      int within = i - tb * 5120;
      int pp = within & 3;
      int lane2 = (within >> 2) & 63;
      int ktm = within >> 8;        // (m*10+kt) in 0..19
      int kt = ktm % 10;
      int k0 = kt * 32 + (lane2 >> 4) * 8 + pp * 2;
      v = (k0 >= 300) ? 0u : HSENT;
    }
    hbz[i] = v;
  }
  conv_seg(words, cw, 1228800, is32, t0, stride);
  conv_seg(vocab, cv, 6000000, is32, t0, stride);
  conv_seg(de, cde, 300, is32, t0, stride);
  conv_seg(W, cW, 90000, is32, t0, stride);
  conv_seg(lWih, cWih, 360000, is32, t0, stride);
  conv_seg(lWhh, cWhh, 360000, is32, t0, stride);
  conv_seg(lbih, cbih, 1200, is32, t0, stride);
  conv_seg(lbhh, cbhh, 1200, is32, t0, stride);
  conv_seg(rWih, crWih, 90000, is32, t0, stride);
  conv_seg(rWhh, crWhh, 90000, is32, t0, stride);
  conv_seg(rbih, crbih, 300, is32, t0, stride);
  conv_seg(rbhh, crbhh, 300, is32, t0, stride);
}

// ---------- transpose bf16 (J x K) -> bf16 (K x J) ----------
__global__ __launch_bounds__(256) void k_transpose_bf(const u16* __restrict__ in,
                                                      u16* __restrict__ out,
                                                      int J, int K) {
  __shared__ u16 t[32][33];
  int j0 = blockIdx.x * 32, k0 = blockIdx.y * 32;
  int lx = threadIdx.x & 31, ly = threadIdx.x >> 5;
  for (int r = ly; r < 32; r += 8) {
    int j = j0 + r, k = k0 + lx;
    t[r][lx] = (j < J && k < K) ? in[(size_t)j * K + k] : (u16)0;
  }
  __syncthreads();
  for (int r = ly; r < 32; r += 8) {
    int k = k0 + r, j = j0 + lx;
    if (k < K && j < J) out[(size_t)k * J + j] = t[lx][r];
  }
}

// ---------- pack lstm_Whh -> per-block gate-interleaved MFMA B-frags (f16) ----------
// Block bid owns dims [38*bid, +nd) (nd=38, last 34). Local col nl = dd*4 + gate
// (160 cols, 10 wave-tiles). pW[bid*51200 + ((w*10+kt)*64 + lane)*8 + j] f16.
// n16=lane&15, quad=lane>>4: g=n16&3, dd=w*4+(n16>>2); dim=38*bid+dd;
// k = kt*32 + quad*8 + j; val = Whh[g*300+dim][k] (0 if dd>=nd or k>=300).
__global__ __launch_bounds__(256) void k_pack_w9(const u16* __restrict__ Whh,
                                                 u16* __restrict__ pW) {
  int idx = blockIdx.x * 256 + threadIdx.x;
  if (idx >= 409600) return;
  int bid = idx / 51200;
  int r = idx - bid * 51200;
  int j = r & 7;
  int lane = (r >> 3) & 63;
  int t2 = r >> 9;           // w*10 + kt
  int kt = t2 % 10, w = t2 / 10;
  int n16 = lane & 15, quad = lane >> 4;
  int g = n16 & 3;
  int dd = w * 4 + (n16 >> 2);
  int nd = (bid < 7) ? 38 : 34;
  int dim = 38 * bid + dd;
  int k = kt * 32 + quad * 8 + j;
  u16 out = 0;
  if (dd < nd && k < 300)
    out = f2h(bf2f(Whh[(size_t)(g * 300 + dim) * 300 + k]));
  pW[idx] = out;
}

// ---------- pack vocab into MFMA operand layouts ----------
__global__ __launch_bounds__(256) void k_pack_vocab(const u16* __restrict__ vocab,
                                                    u16* __restrict__ pA,
                                                    u16* __restrict__ pB) {
  __shared__ u16 sv[32][320];
  int ci = blockIdx.x, tid = threadIdx.x;
  for (int idx = tid; idx < 32 * 20; idx += 256) {
    int v = idx / 20, k = 300 + (idx - v * 20);
    sv[v][k] = 0;
  }
  for (int idx = tid; idx < 32 * 300; idx += 256) {
    int v = idx / 300, k = idx - v * 300;
    sv[v][k] = vocab[(size_t)(ci * 32 + v) * 300 + k];
  }
  __syncthreads();
  for (int idx = tid; idx < 10240; idx += 256) {
    int j = idx & 7, lane = (idx >> 3) & 63, t2 = idx >> 9;
    int kk = t2 % 10, h = t2 / 10;
    int v = h * 16 + (lane & 15);
    int k = kk * 32 + ((lane >> 4)) * 8 + j;
    pA[(size_t)ci * 10240 + (size_t)idx] = sv[v][k];
  }
  for (int idx = tid; idx < 9728; idx += 256) {
    int j = idx & 7, lane = (idx >> 3) & 63, nc = idx >> 9;
    int v = (lane >> 4) * 8 + j;
    int n = nc * 16 + (lane & 15);
    pB[(size_t)ci * 9728 + (size_t)idx] = sv[v][n];
  }
}

// ---------- X = words @ W -> bf16 (4096 x 320, zero pad) ----------
__global__ __launch_bounds__(256) void k_xw(const u16* __restrict__ words,
                                            const u16* __restrict__ W,
                                            u16* __restrict__ X) {
  __shared__ float As[300][33];
  int n0 = blockIdx.x * 128;
  int r0 = blockIdx.y * 32;
  int tid = threadIdx.x;
  for (int idx = tid; idx < 32 * 300; idx += 256) {
    int r = idx / 300, k = idx - r * 300;
    As[k][r] = bf2f(words[(size_t)(r0 + r) * 300 + k]);
  }
  __syncthreads();
  int j = n0 + (tid & 127);
  int rh = (tid >> 7) * 16;
  float acc[16];
#pragma unroll
  for (int i = 0; i < 16; i++) acc[i] = 0.f;
  if (j < 300) {
    for (int k = 0; k < 300; k++) {
      float bw = bf2f(W[(size_t)k * 300 + j]);
#pragma unroll
      for (int i = 0; i < 16; i++) acc[i] += As[k][rh + i] * bw;
    }
  }
  if (j < 320) {
#pragma unroll
    for (int i = 0; i < 16; i++) {
      float v = (j < 300) ? acc[i] : 0.f;
      X[(size_t)(r0 + rh + i) * 320 + j] = f2bf(v);
    }
  }
}

// ---------- flash-style softmax-weighted vocab sum (MFMA), per-slice partials ----------
__global__ __launch_bounds__(512, 2) void k_softmax_v(
    const u16* __restrict__ X, const u16* __restrict__ pA, const u16* __restrict__ pB,
    u16* __restrict__ pAcc, float* __restrict__ pML) {
  __shared__ __align__(16) u16 chunk[19968];
  __shared__ __align__(16) float ptbuf[8 * 576];
  int bid = blockIdx.x;
  int sl = bid & 7, b = bid >> 3;
  int tid = threadIdx.x;
  int w = tid >> 6, lane = tid & 63;
  int quad = lane >> 4, n16 = lane & 15;
  int cs = (sl == 0) ? 0 : 79 + (sl - 1) * 78;
  int nch = (sl == 0) ? 79 : 78;

  int rowA = b * 128 + w * 16 + n16;
  const bf16x8* Xrow = (const bf16x8*)(X + (size_t)rowA * 320);
  bf16x8 afr[10];
#pragma unroll
  for (int kk = 0; kk < 10; kk++) afr[kk] = Xrow[kk * 4 + quad];

  f32x4 acc[19];
#pragma unroll
  for (int i = 0; i < 19; i++) { acc[i][0] = 0.f; acc[i][1] = 0.f; acc[i][2] = 0.f; acc[i][3] = 0.f; }
  f32x4 mrun, lrun;
#pragma unroll
  for (int c = 0; c < 4; c++) { mrun[c] = -1e30f; lrun[c] = 0.f; }
  float* myPt = ptbuf + w * 576;

  {
    const u32x4* gA = (const u32x4*)pA + (size_t)cs * 1280;
    const u32x4* gB = (const u32x4*)pB + (size_t)cs * 1216;
    u32x4* sb = (u32x4*)&chunk[0];
    for (int idx = tid; idx < 2496; idx += 512)
      sb[idx] = (idx < 1280) ? gA[idx] : gB[idx - 1280];
  }
  __syncthreads();

  for (int ic = 0; ic < nch; ic++) {
    u32x4 pf[5];
    bool havepf = (ic + 1 < nch);
    if (havepf) {
      int ci = cs + ic + 1;
      const u32x4* gA = (const u32x4*)pA + (size_t)ci * 1280;
      const u32x4* gB = (const u32x4*)pB + (size_t)ci * 1216;
#pragma unroll
      for (int i = 0; i < 5; i++) {
        int idx = tid + i * 512;
        if (idx < 2496) pf[i] = (idx < 1280) ? gA[idx] : gB[idx - 1280];
      }
    }
    const bf16x8* bufA = (const bf16x8*)&chunk[0];
    const bf16x8* bufB = (const bf16x8*)&chunk[10240];
    f32x4 L0, L1;
#pragma unroll
    for (int c = 0; c < 4; c++) { L0[c] = 0.f; L1[c] = 0.f; }
#pragma unroll
    for (int kk = 0; kk < 10; kk++) {
      L0 = __builtin_amdgcn_mfma_f32_16x16x32_bf16(afr[kk], bufA[kk * 64 + lane], L0, 0, 0, 0);
      L1 = __builtin_amdgcn_mfma_f32_16x16x32_bf16(afr[kk], bufA[(10 + kk) * 64 + lane], L1, 0, 0, 0);
    }
    f32x4 t;
#pragma unroll
    for (int c = 0; c < 4; c++) t[c] = fmaxf(L0[c], L1[c]);
#pragma unroll
    for (int off = 1; off < 16; off <<= 1) {
      f32x4 o = shflx4(t, off);
#pragma unroll
      for (int c = 0; c < 4; c++) t[c] = fmaxf(t[c], o[c]);
    }
    f32x4 mnew, al, P0v, P1v, rs;
#pragma unroll
    for (int c = 0; c < 4; c++) {
      mnew[c] = fmaxf(mrun[c], t[c]);
      al[c] = __expf(mrun[c] - mnew[c]);
      P0v[c] = __expf(L0[c] - mnew[c]);
      P1v[c] = __expf(L1[c] - mnew[c]);
      rs[c] = P0v[c] + P1v[c];
    }
#pragma unroll
    for (int off = 1; off < 16; off <<= 1) {
      f32x4 o = shflx4(rs, off);
#pragma unroll
      for (int c = 0; c < 4; c++) rs[c] += o[c];
    }
#pragma unroll
    for (int c = 0; c < 4; c++) { lrun[c] = lrun[c] * al[c] + rs[c]; mrun[c] = mnew[c]; }
#pragma unroll
    for (int r = 0; r < 4; r++) {
      myPt[(quad * 4 + r) * 36 + n16] = P0v[r];
      myPt[(quad * 4 + r) * 36 + 16 + n16] = P1v[r];
    }
    __syncthreads();
    f32x4 plo = *(const f32x4*)(myPt + n16 * 36 + quad * 8);
    f32x4 phi = *(const f32x4*)(myPt + n16 * 36 + quad * 8 + 4);
    bf16x8 paf;
#pragma unroll
    for (int c = 0; c < 4; c++) { paf[c] = (__bf16)plo[c]; paf[c + 4] = (__bf16)phi[c]; }
#pragma unroll
    for (int nc = 0; nc < 19; nc++) {
      f32x4 a = acc[nc];
#pragma unroll
      for (int c = 0; c < 4; c++) a[c] *= al[c];
      acc[nc] = __builtin_amdgcn_mfma_f32_16x16x32_bf16(paf, bufB[nc * 64 + lane], a, 0, 0, 0);
    }
    __syncthreads();
    if (havepf) {
      u32x4* sb = (u32x4*)&chunk[0];
#pragma unroll
      for (int i = 0; i < 5; i++) {
        int idx = tid + i * 512;
        if (idx < 2496) sb[idx] = pf[i];
      }
    }
    __syncthreads();
  }

  size_t prow = (size_t)sl * 4096 + (size_t)b * 128 + w * 16;
  if (n16 == 0) {
#pragma unroll
    for (int r = 0; r < 4; r++) {
      pML[(prow + quad * 4 + r) * 2 + 0] = mrun[r];
      pML[(prow + quad * 4 + r) * 2 + 1] = lrun[r];
    }
  }
#pragma unroll
  for (int nc = 0; nc < 19; nc++)
#pragma unroll
    for (int r = 0; r < 4; r++)
      pAcc[(prow + quad * 4 + r) * 304 + nc * 16 + n16] = f2bf(acc[nc][r]);
}

// ---------- combine slices + default-embed column -> V bf16 (4096 x 320) ----------
__global__ __launch_bounds__(320) void k_combine(
    const u16* __restrict__ pAcc, const float* __restrict__ pML,
    const u16* __restrict__ X, const u16* __restrict__ de,
    const u16* __restrict__ words, u16* __restrict__ Vout) {
  __shared__ float red[320];
  __shared__ float fs[8];
  __shared__ float sinv, sw;
  int row = blockIdx.x, tid = threadIdx.x;
  float p = 0.f;
  if (tid < 300) p = bf2f(X[(size_t)row * 320 + tid]) * bf2f(de[tid]);
  red[tid] = p;
  __syncthreads();
  if (tid == 0) {
    float d = 0.f;
    for (int i = 0; i < 300; i++) d += red[i];
    float mv[8], lv[8], ms = -1e30f;
    for (int s = 0; s < 8; s++) {
      mv[s] = pML[((size_t)s * 4096 + row) * 2];
      lv[s] = pML[((size_t)s * 4096 + row) * 2 + 1];
      ms = fmaxf(ms, mv[s]);
    }
    float mf = fmaxf(ms, d);
    float pd = __expf(d - mf);
    float l = pd;
    for (int s = 0; s < 8; s++) {
      float f = __expf(mv[s] - mf);
      fs[s] = f;
      l += lv[s] * f;
    }
    sinv = 1.f / l;
    sw = pd / l;
  }
  __syncthreads();
  float v = 0.f;
  if (tid < 300) {
    float a = 0.f;
#pragma unroll
    for (int s = 0; s < 8; s++)
      a += bf2f(pAcc[((size_t)s * 4096 + row) * 304 + tid]) * fs[s];
    v = a * sinv + sw * bf2f(words[(size_t)row * 300 + tid]);
  }
  Vout[(size_t)row * 320 + tid] = f2bf(v);
}

// ---------- xg = V @ lstm_Wih.T + biases, written directly in MFMA C-init layout ----
// xgp[((t*8 + bid)*2 + m)*2560 + nl*16 + b16], nl = dd*4 + gate (gate-interleaved).
__global__ __launch_bounds__(256) void k_xg(const u16* __restrict__ Vb,
                                            const u16* __restrict__ WihT,
                                            const u16* __restrict__ bih,
                                            const u16* __restrict__ bhh,
                                            float* __restrict__ xgp) {
  __shared__ float As[300][33];
  int n0 = blockIdx.x * 128;
  int r0 = blockIdx.y * 32;
  int tid = threadIdx.x;
  for (int idx = tid; idx < 32 * 300; idx += 256) {
    int r = idx / 300, k = idx - r * 300;
    As[k][r] = bf2f(Vb[(size_t)(r0 + r) * 320 + k]);
  }
  __syncthreads();
  int j = n0 + (tid & 127);
  if (j >= 1200) return;
  int rh = (tid >> 7) * 16;
  float acc[16];
#pragma unroll
  for (int i = 0; i < 16; i++) acc[i] = 0.f;
  for (int k = 0; k < 300; k++) {
    float bw = bf2f(WihT[(size_t)k * 1200 + j]);
#pragma unroll
    for (int i = 0; i < 16; i++) acc[i] += As[k][rh + i] * bw;
  }
  float bias = bf2f(bih[j]) + bf2f(bhh[j]);
  int gate = j / 300, dimm = j - gate * 300;
  int bid = dimm / 38; if (bid > 7) bid = 7;
  int dd = dimm - 38 * bid;
  int nl = dd * 4 + gate;
#pragma unroll
  for (int i = 0; i < 16; i++) {
    int r = r0 + rh + i;
    int t = r & 127, batch = r >> 7;
    xgp[(((size_t)t * 8 + bid) * 2 + (batch >> 4)) * 2560 + nl * 16 + (batch & 15)] =
        acc[i] + bias;
  }
}

// ---------- LSTM: 16 blocks = 2 batch-groups x 8 dim-blocks; dataflow exchange ----------
// No flags, no in-loop barriers. h lives in write-once per-step buffers
// hb[t][m][kt][lane][pp] u32 (2xf16), pre-filled with sentinel 0x7FFF7FFF
// (f16 NaN pair, unreachable: |h|<=1). Producers store h-pairs as one relaxed
// agent-scope u32; consumers load their A-frag dwords and spin per-wave until
// non-sentinel. Gate-interleaved cols + DPP 4x4 transpose -> activations fully
// in-register (no gl LDS). xg enters as the MFMA C initializer (prefetched 1 step).
__global__ __launch_bounds__(640, 1) void k_lstm6(
    const float* __restrict__ xgp, const u16* __restrict__ pW,
    const int* __restrict__ lengths, u32* __restrict__ hb,
    float* __restrict__ qbuf) {
  __shared__ __align__(16) u16 wlds[51200];  // 100 KB B-frags
  __shared__ int s_maxlen;
  int bidx = blockIdx.x;
  int mg = bidx >> 3, bid = bidx & 7;   // batch group, dim block
  int tid = threadIdx.x;
  int w = tid >> 6, lane = tid & 63;
  int quad = lane >> 4, n16 = lane & 15;
  int g = n16 & 3, ddl = n16 >> 2;
  int nd = (bid < 7) ? 38 : 34;
  // stage weights -> LDS (contiguous)
  {
    const u32x4* src = (const u32x4*)(pW + (size_t)bid * 51200);
    u32x4* dst = (u32x4*)wlds;
#pragma unroll
    for (int i = 0; i < 10; i++) dst[tid + i * 640] = src[tid + i * 640];
  }
  // maxlen over all 32 batches (uniform across all blocks)
  {
    int lv = (tid < 32) ? lengths[tid] : 0;
#pragma unroll
    for (int off = 1; off < 32; off <<= 1) {
      int o = __shfl_xor(lv, off, 64);
      lv = lv > o ? lv : o;
    }
    if (tid == 0) s_maxlen = lv;
  }
  int dd = w * 4 + ddl;
  int dim = 38 * bid + dd;
  bool act = dd < nd;
  int b15 = quad * 4 + g;               // batch (group-local) this lane owns
  int len_b = lengths[mg * 16 + b15];
  // producer store index: pair (k0, k0+1), k0 = even dim (even-ddl lanes store)
  int k0 = dim & ~1;
  int sidx = ((mg * 10 + (k0 >> 5)) * 64 + ((k0 >> 3) & 3) * 16 + b15) * 4 + ((k0 >> 1) & 3);
  // xg C-init pointer: f32x4 covering batches quad*4..+3 of col nl = w*16+n16
  const f32x4* xp0 = (const f32x4*)xgp +
                     ((size_t)(bid * 2 + mg) * 2560 + (size_t)(w * 16 + n16) * 16) / 4 + quad;
  f32x4 xv = xp0[0];
  float cc = 0.f, hh = 0.f;
  __syncthreads();
  int maxlen = s_maxlen;
  for (int t = 0; t < maxlen; t++) {
    f32x4 C = xv;
    if (t + 1 < maxlen) xv = xp0[(size_t)(t + 1) * 10240];  // prefetch next step
    // A-frags: h_t for 16 batches of this group; spin until all non-sentinel
    const u32* hbt = hb + (size_t)t * 5120;
    u32 af[10][4];
#pragma unroll
    for (int kt = 0; kt < 10; kt++)
#pragma unroll
      for (int pp = 0; pp < 4; pp++)
        af[kt][pp] = __hip_atomic_load(hbt + ((mg * 10 + kt) * 64 + lane) * 4 + pp,
                                       __ATOMIC_RELAXED, SCOPE_AGENT);
    while (true) {
      u32 bad = 0;
#pragma unroll
      for (int kt = 0; kt < 10; kt++)
#pragma unroll
        for (int pp = 0; pp < 4; pp++) bad |= (af[kt][pp] == HSENT) ? 1u : 0u;
      if (!__any(bad)) break;
      __builtin_amdgcn_s_sleep(1);
#pragma unroll
      for (int kt = 0; kt < 10; kt++)
#pragma unroll
        for (int pp = 0; pp < 4; pp++)
          if (af[kt][pp] == HSENT)
            af[kt][pp] = __hip_atomic_load(hbt + ((mg * 10 + kt) * 64 + lane) * 4 + pp,
                                           __ATOMIC_RELAXED, SCOPE_AGENT);
    }
    // MFMA: 10 K-frags, B from LDS, C-init = xg
    const u32x4* wl = (const u32x4*)wlds;
#pragma unroll
    for (int kt = 0; kt < 10; kt++) {
      u32x4 a4;
      a4[0] = af[kt][0]; a4[1] = af[kt][1]; a4[2] = af[kt][2]; a4[3] = af[kt][3];
      f16x8 bfr = __builtin_bit_cast(f16x8, wl[(w * 10 + kt) * 64 + lane]);
      C = __builtin_amdgcn_mfma_f32_16x16x32_f16(
          __builtin_bit_cast(f16x8, a4), bfr, C, 0, 0, 0);
    }
    // DPP 4x4 transpose: lane g gets all 4 gates of batch quad*4+g (verified lstm3/4)
    float v0 = C[0], v1 = C[1], v2 = C[2], v3 = C[3];
    float x0 = dppq<0xB1>(v0), x1 = dppq<0xB1>(v1);
    float x2 = dppq<0xB1>(v2), x3 = dppq<0xB1>(v3);
    bool o1 = (g & 1);
    float m0 = o1 ? x1 : v0;
    float m1 = o1 ? v1 : x0;
    float m2 = o1 ? x3 : v2;
    float m3 = o1 ? v3 : x2;
    float y0 = dppq<0x4E>(m0), y1 = dppq<0x4E>(m1);
    float y2 = dppq<0x4E>(m2), y3 = dppq<0x4E>(m3);
    bool o2 = (g & 2);
    float F0 = o2 ? y2 : m0;  // i
    float F1 = o2 ? y3 : m1;  // f
    float F2 = o2 ? m2 : y0;  // g
    float F3 = o2 ? m3 : y1;  // o
    float ii = sigm_fast(F0), ff = sigm_fast(F1);
    float gg = tanh_fast(F2), oo = sigm_fast(F3);
    float cn = ff * cc + ii * gg;
    float hn = oo * tanh_fast(cn);
    if (t < len_b) { cc = cn; hh = hn; }
    // publish h pair (even-ddl lane packs partner's h via lane^4 exchange)
    u32 myh = (u32)f2h(hh);
    u32 oth = (u32)__shfl_xor((int)myh, 4, 64);
    if (((ddl & 1) == 0) && act) {
      u32 pair = myh | (oth << 16);
      __hip_atomic_store(hb + (size_t)(t + 1) * 5120 + sidx, pair,
                         __ATOMIC_RELAXED, SCOPE_AGENT);
    }
  }
  // final q (h frozen at len per batch)
  if (act) qbuf[(size_t)(mg * 16 + b15) * 304 + dim] = hh;
}

// ---------- RNN tail: q from qbuf (f32), 8 steps h2 = tanh(base + h2@rWhh.T) ----------
__global__ __launch_bounds__(320) void k_rnn(
    const float* __restrict__ qbuf,
    const u16* __restrict__ rWihT, const u16* __restrict__ rWhhT,
    const u16* __restrict__ rbih, const u16* __restrict__ rbhh,
    float* __restrict__ H) {
  __shared__ float qs[304], h2[304], base[304];
  int b = blockIdx.x, tid = threadIdx.x;
  if (tid < 304) {
    qs[tid] = (tid < 300) ? qbuf[(size_t)b * 304 + tid] : 0.f;
    h2[tid] = 0.f;
  }
  __syncthreads();
  if (tid < 300) {
    float a = bf2f(rbih[tid]) + bf2f(rbhh[tid]);
    for (int k = 0; k < 300; k++) a += qs[k] * bf2f(rWihT[(size_t)k * 300 + tid]);
    base[tid] = a;
  }
  __syncthreads();
  for (int s = 0; s < 8; s++) {
    float nv = 0.f;
    if (tid < 300) {
      float a = base[tid];
      for (int k = 0; k < 300; k++) a += h2[k] * bf2f(rWhhT[(size_t)k * 300 + tid]);
      nv = tanhf(a);
    }
    __syncthreads();
    if (tid < 300) {
      h2[tid] = nv;
      H[((size_t)b * 8 + s) * 300 + tid] = nv;
    }
    __syncthreads();
  }
}

// ---------- attention readout ----------
__global__ __launch_bounds__(256) void k_attn(const float* __restrict__ H,
                                              const u16* __restrict__ Vb,
                                              const int* __restrict__ lengths,
                                              const u32* __restrict__ flag,
                                              void* __restrict__ dout) {
  __shared__ float Hs[8][304];
  __shared__ float sc[8][128];
  __shared__ float wsum[8];
  int b = blockIdx.x, tid = threadIdx.x;
  int len = lengths[b];
  int is32 = (int)*flag;
  for (int idx = tid; idx < 8 * 300; idx += 256) {
    int k = idx / 300, j = idx - k * 300;
    Hs[k][j] = H[((size_t)b * 8 + k) * 300 + j];
  }
  __syncthreads();
  for (int s = tid; s < len; s += 256) {
    const u16* vr = Vb + (size_t)(b * 128 + s) * 320;
    float a[8];
#pragma unroll
    for (int k = 0; k < 8; k++) a[k] = 0.f;
    for (int j = 0; j < 300; j++) {
      float v = bf2f(vr[j]);
#pragma unroll
      for (int k = 0; k < 8; k++) a[k] += Hs[k][j] * v;
    }
#pragma unroll
    for (int k = 0; k < 8; k++) sc[k][s] = a[k];
  }
  __syncthreads();
  if (tid < 8) {
    float m = -1e30f;
    for (int s = 0; s < len; s++) m = fmaxf(m, sc[tid][s]);
    float l = 0.f;
    for (int s = 0; s < len; s++) { float e = __expf(sc[tid][s] - m); sc[tid][s] = e; l += e; }
    wsum[tid] = 1.f / l;
  }
  __syncthreads();
  int k = tid >> 5, jl = tid & 31;
  for (int j = jl; j < 300; j += 32) {
    float a = 0.f;
    for (int s = 0; s < len; s++) a += sc[k][s] * bf2f(Vb[(size_t)(b * 128 + s) * 320 + j]);
    float val = a * wsum[k];
    size_t o = ((size_t)b * 8 + k) * 300 + j;
    if (is32) ((float*)dout)[o] = val;
    else ((u16*)dout)[o] = f2bf(val);
  }
}

extern "C" void kernel_launch(void* const* d_in, const int* in_sizes, int n_in,
                              void* d_out, int out_size, void* d_ws, size_t ws_size,
                              hipStream_t stream) {
  (void)in_sizes; (void)n_in; (void)out_size; (void)ws_size;
  const void* words = d_in[0];
  const int* lengths = (const int*)d_in[1];
  const void* vocab = d_in[2];
  const void* de = d_in[3];
  const void* W = d_in[4];
  const void* lWih = d_in[5];
  const void* lWhh = d_in[6];
  const void* lbih = d_in[7];
  const void* lbhh = d_in[8];
  const void* rWih = d_in[9];
  const void* rWhh = d_in[10];
  const void* rbih = d_in[11];
  const void* rbhh = d_in[12];

  char* basep = (char*)d_ws;
  size_t off = 0;
  auto take = [&](size_t bytes) -> char* {
    char* p = basep + off;
    off += (bytes + 255) & ~(size_t)255;
    return p;
  };
  u16* cw    = (u16*)take(1228800 * 2);
  u16* cv    = (u16*)take(6000000 * 2);
  u16* cde   = (u16*)take(300 * 2);
  u16* cW    = (u16*)take(90000 * 2);
  u16* cWih  = (u16*)take(360000 * 2);
  u16* cWhh  = (u16*)take(360000 * 2);
  u16* cbih  = (u16*)take(1200 * 2);
  u16* cbhh  = (u16*)take(1200 * 2);
  u16* crWih = (u16*)take(90000 * 2);
  u16* crWhh = (u16*)take(90000 * 2);
  u16* crbih = (u16*)take(300 * 2);
  u16* crbhh = (u16*)take(300 * 2);
  u32* flag  = (u32*)take(256);
  u16*   X     = (u16*)take((size_t)4096 * 320 * 2);
  u16*   Vb    = (u16*)take((size_t)4096 * 320 * 2);
  u16*   WihT  = (u16*)take((size_t)300 * 1200 * 2);
  u16*   pW9   = (u16*)take((size_t)409600 * 2);
  u16*   rWihT = (u16*)take((size_t)300 * 300 * 2);
  u16*   rWhhT = (u16*)take((size_t)300 * 300 * 2);
  u16*   pAcc  = (u16*)take((size_t)8 * 4096 * 304 * 2);
  float* pML   = (float*)take((size_t)8 * 4096 * 2 * 4);
  float* H     = (float*)take((size_t)32 * 8 * 300 * 4);
  float* qbuf  = (float*)take((size_t)32 * 304 * 4);
  u32*   hb    = (u32*)take((size_t)660480 * 4);  // 129 steps x 5120 u32 dataflow bufs
  // union region: pA+pB (dead after k_softmax_v), then xgp (C-init layout)
  char* ureg = take((size_t)25000192);
  u16*   pA = (u16*)ureg;
  u16*   pB = (u16*)(ureg + (size_t)625 * 10240 * 2);
  float* xgp = (float*)ureg;

  k_ingest<<<4096, 256, 0, stream>>>(words, vocab, de, W, lWih, lWhh, lbih, lbhh,
                                     rWih, rWhh, rbih, rbhh,
                                     cw, cv, cde, cW, cWih, cWhh, cbih, cbhh,
                                     crWih, crWhh, crbih, crbhh, flag, hb);
  k_transpose_bf<<<dim3(38, 10), 256, 0, stream>>>(cWih, WihT, 1200, 300);
  k_transpose_bf<<<dim3(10, 10), 256, 0, stream>>>(crWih, rWihT, 300, 300);
  k_transpose_bf<<<dim3(10, 10), 256, 0, stream>>>(crWhh, rWhhT, 300, 300);
  k_pack_w9<<<1600, 256, 0, stream>>>(cWhh, pW9);
  k_pack_vocab<<<625, 256, 0, stream>>>(cv, pA, pB);
  k_xw<<<dim3(3, 128), 256, 0, stream>>>(cw, cW, X);
  k_softmax_v<<<256, 512, 0, stream>>>(X, pA, pB, pAcc, pML);
  k_combine<<<4096, 320, 0, stream>>>(pAcc, pML, X, cde, cw, Vb);
  k_xg<<<dim3(10, 128), 256, 0, stream>>>(Vb, WihT, cbih, cbhh, xgp);
  k_lstm6<<<16, 640, 0, stream>>>(xgp, pW9, lengths, hb, qbuf);
  k_rnn<<<32, 320, 0, stream>>>(qbuf, rWihT, rWhhT, crbih, crbhh, H);
  k_attn<<<32, 256, 0, stream>>>(H, Vb, lengths, flag, d_out);
}

// Round 7
// 1074.200 us; speedup vs baseline: 1.6555x; 1.6555x over previous
//
#include <hip/hip_runtime.h>

// B=32, S=128, D=300 (pad 320), VOCAB=20000 (625 chunks of 32), K=8.
// Inputs may be f32 or bf16 (runtime-detected); canonicalized to bf16 in ws.

typedef unsigned short u16;
typedef unsigned int   u32;
typedef float  f32x4 __attribute__((ext_vector_type(4)));
typedef u32    u32x4 __attribute__((ext_vector_type(4)));
typedef __bf16 bf16x8 __attribute__((ext_vector_type(8)));
typedef _Float16 f16x2 __attribute__((ext_vector_type(2)));
typedef _Float16 f16x8 __attribute__((ext_vector_type(8)));

#define SCOPE_AGENT __HIP_MEMORY_SCOPE_AGENT

__device__ __forceinline__ float bf2f(u16 u) { return __uint_as_float(((u32)u) << 16); }
__device__ __forceinline__ u16 f2bf(float f) {
  u32 x = __float_as_uint(f);
  u32 r = (x + 0x7fffu + ((x >> 16) & 1u)) >> 16;  // RNE
  return (u16)r;
}
__device__ __forceinline__ float sigm(float x) { return 1.f / (1.f + __expf(-x)); }
__device__ __forceinline__ u16 f2h(float f) {
  union { _Float16 h; u16 u; } cv; cv.h = (_Float16)f; return cv.u;
}
__device__ __forceinline__ float h2f(u16 u) {
  union { _Float16 h; u16 u; } cv; cv.u = u; return (float)cv.h;
}

__device__ __forceinline__ f32x4 shflx4(f32x4 v, int m) {
  f32x4 r;
  r[0] = __shfl_xor(v[0], m, 16);
  r[1] = __shfl_xor(v[1], m, 16);
  r[2] = __shfl_xor(v[2], m, 16);
  r[3] = __shfl_xor(v[3], m, 16);
  return r;
}

// ---------- ingest: detect f32 vs bf16, canonicalize all float inputs to bf16 ----------
__device__ __forceinline__ void conv_seg(const void* src, u16* dst, int n, int is32,
                                         int t0, int stride) {
  if (is32) {
    const float* s = (const float*)src;
    for (int i = t0; i < n; i += stride) dst[i] = f2bf(s[i]);
  } else {
    const u16* s = (const u16*)src;
    for (int i = t0; i < n; i += stride) dst[i] = s[i];
  }
}

__global__ __launch_bounds__(256) void k_ingest(
    const void* words, const void* vocab, const void* de, const void* W,
    const void* lWih, const void* lWhh, const void* lbih, const void* lbhh,
    const void* rWih, const void* rWhh, const void* rbih, const void* rbhh,
    u16* cw, u16* cv, u16* cde, u16* cW, u16* cWih, u16* cWhh, u16* cbih, u16* cbhh,
    u16* crWih, u16* crWhh, u16* crbih, u16* crbhh, u32* flag, u32* seqz, u32* hbz) {
  __shared__ int s_is32;
  int tid = threadIdx.x;
  int vote = 0;
  if (tid < 64) {
    u32 w = ((const u32*)words)[tid];
    int e = (w >> 7) & 0xFF;  // bf16 low-element exponent field if bf16-packed
    vote = (e >= 100 && e <= 150) ? 1 : 0;
  }
  unsigned long long m = __ballot(vote);
  if (tid == 0) s_is32 = (__popcll(m) < 32) ? 1 : 0;  // few plausible bf16 exps -> f32
  __syncthreads();
  int is32 = s_is32;
  if (blockIdx.x == 0 && tid == 0) *flag = (u32)is32;
  int t0 = blockIdx.x * 256 + tid;
  int stride = gridDim.x * 256;
  if (t0 < 256) seqz[t0] = 0;     // LSTM step counters
  if (t0 < 10240) hbz[t0] = 0;    // LSTM h exchange buffers (f16 A-layout, both bufs)
  conv_seg(words, cw, 1228800, is32, t0, stride);
  conv_seg(vocab, cv, 6000000, is32, t0, stride);
  conv_seg(de, cde, 300, is32, t0, stride);
  conv_seg(W, cW, 90000, is32, t0, stride);
  conv_seg(lWih, cWih, 360000, is32, t0, stride);
  conv_seg(lWhh, cWhh, 360000, is32, t0, stride);
  conv_seg(lbih, cbih, 1200, is32, t0, stride);
  conv_seg(lbhh, cbhh, 1200, is32, t0, stride);
  conv_seg(rWih, crWih, 90000, is32, t0, stride);
  conv_seg(rWhh, crWhh, 90000, is32, t0, stride);
  conv_seg(rbih, crbih, 300, is32, t0, stride);
  conv_seg(rbhh, crbhh, 300, is32, t0, stride);
}

// ---------- transpose bf16 (J x K) -> bf16 (K x J) ----------
__global__ __launch_bounds__(256) void k_transpose_bf(const u16* __restrict__ in,
                                                      u16* __restrict__ out,
                                                      int J, int K) {
  __shared__ u16 t[32][33];
  int j0 = blockIdx.x * 32, k0 = blockIdx.y * 32;
  int lx = threadIdx.x & 31, ly = threadIdx.x >> 5;
  for (int r = ly; r < 32; r += 8) {
    int j = j0 + r, k = k0 + lx;
    t[r][lx] = (j < J && k < K) ? in[(size_t)j * K + k] : (u16)0;
  }
  __syncthreads();
  for (int r = ly; r < 32; r += 8) {
    int k = k0 + r, j = j0 + lx;
    if (k < K && j < J) out[(size_t)k * J + j] = t[lx][r];
  }
}

// ---------- pack lstm_Whh -> per-block MFMA B-frag slices (f16) ----------
// pW[bid=16][(nt*10+kt)*64+lane][8] f16; n = nt*16+(lane&15); gate=n/20; dl=n%20;
// dim = d0(bid)+dl; k = kt*32+(lane>>4)*8+j; val = Whh[gate*300+dim][k] (0 pad).
__global__ __launch_bounds__(256) void k_pack_w4(const u16* __restrict__ Whh,
                                                 u16* __restrict__ pW) {
  int idx = blockIdx.x * 256 + threadIdx.x;
  if (idx >= 16 * 25600) return;
  int bid = idx / 25600, r = idx % 25600;
  int t2 = r >> 9, lane = (r >> 3) & 63, j = r & 7;
  int nt = t2 / 10, kt = t2 % 10;
  int n = nt * 16 + (lane & 15);
  int gate = n / 20, dl = n % 20;
  int d0 = (bid < 15) ? 19 * bid : 285;
  int nd = (bid < 15) ? 19 : 15;
  int k = kt * 32 + ((lane >> 4) * 8) + j;
  u16 out = 0;
  if (dl < nd && k < 300) out = f2h(bf2f(Whh[(size_t)(gate * 300 + d0 + dl) * 300 + k]));
  pW[idx] = out;
}

// ---------- pack vocab into MFMA operand layouts ----------
__global__ __launch_bounds__(256) void k_pack_vocab(const u16* __restrict__ vocab,
                                                    u16* __restrict__ pA,
                                                    u16* __restrict__ pB) {
  __shared__ u16 sv[32][320];
  int ci = blockIdx.x, tid = threadIdx.x;
  for (int idx = tid; idx < 32 * 20; idx += 256) {
    int v = idx / 20, k = 300 + (idx - v * 20);
    sv[v][k] = 0;
  }
  for (int idx = tid; idx < 32 * 300; idx += 256) {
    int v = idx / 300, k = idx - v * 300;
    sv[v][k] = vocab[(size_t)(ci * 32 + v) * 300 + k];
  }
  __syncthreads();
  for (int idx = tid; idx < 10240; idx += 256) {
    int j = idx & 7, lane = (idx >> 3) & 63, t2 = idx >> 9;
    int kk = t2 % 10, h = t2 / 10;
    int v = h * 16 + (lane & 15);
    int k = kk * 32 + ((lane >> 4)) * 8 + j;
    pA[(size_t)ci * 10240 + (size_t)idx] = sv[v][k];
  }
  for (int idx = tid; idx < 9728; idx += 256) {
    int j = idx & 7, lane = (idx >> 3) & 63, nc = idx >> 9;
    int v = (lane >> 4) * 8 + j;
    int n = nc * 16 + (lane & 15);
    pB[(size_t)ci * 9728 + (size_t)idx] = sv[v][n];
  }
}

// ---------- X = words @ W -> bf16 (4096 x 320, zero pad) ----------
__global__ __launch_bounds__(256) void k_xw(const u16* __restrict__ words,
                                            const u16* __restrict__ W,
                                            u16* __restrict__ X) {
  __shared__ float As[300][33];
  int n0 = blockIdx.x * 128;
  int r0 = blockIdx.y * 32;
  int tid = threadIdx.x;
  for (int idx = tid; idx < 32 * 300; idx += 256) {
    int r = idx / 300, k = idx - r * 300;
    As[k][r] = bf2f(words[(size_t)(r0 + r) * 300 + k]);
  }
  __syncthreads();
  int j = n0 + (tid & 127);
  int rh = (tid >> 7) * 16;
  float acc[16];
#pragma unroll
  for (int i = 0; i < 16; i++) acc[i] = 0.f;
  if (j < 300) {
    for (int k = 0; k < 300; k++) {
      float bw = bf2f(W[(size_t)k * 300 + j]);
#pragma unroll
      for (int i = 0; i < 16; i++) acc[i] += As[k][rh + i] * bw;
    }
  }
  if (j < 320) {
#pragma unroll
    for (int i = 0; i < 16; i++) {
      float v = (j < 300) ? acc[i] : 0.f;
      X[(size_t)(r0 + rh + i) * 320 + j] = f2bf(v);
    }
  }
}

// ---------- flash-style softmax-weighted vocab sum (MFMA), per-slice partials ----------
// Double-buffered chunk LDS: read chunk[cur], stage prefetch into chunk[cur^1],
// ONE barrier per iteration (was 3). ptbuf is wave-private (w*576) -> no barrier
// needed around it (same-wave LDS ordering via lgkmcnt).
__global__ __launch_bounds__(512, 2) void k_softmax_v(
    const u16* __restrict__ X, const u16* __restrict__ pA, const u16* __restrict__ pB,
    u16* __restrict__ pAcc, float* __restrict__ pML) {
  __shared__ __align__(16) u16 chunk[2][19968];
  __shared__ __align__(16) float ptbuf[8 * 576];
  int bid = blockIdx.x;
  int sl = bid & 7, b = bid >> 3;
  int tid = threadIdx.x;
  int w = tid >> 6, lane = tid & 63;
  int quad = lane >> 4, n16 = lane & 15;
  int cs = (sl == 0) ? 0 : 79 + (sl - 1) * 78;
  int nch = (sl == 0) ? 79 : 78;

  int rowA = b * 128 + w * 16 + n16;
  const bf16x8* Xrow = (const bf16x8*)(X + (size_t)rowA * 320);
  bf16x8 afr[10];
#pragma unroll
  for (int kk = 0; kk < 10; kk++) afr[kk] = Xrow[kk * 4 + quad];

  f32x4 acc[19];
#pragma unroll
  for (int i = 0; i < 19; i++) { acc[i][0] = 0.f; acc[i][1] = 0.f; acc[i][2] = 0.f; acc[i][3] = 0.f; }
  f32x4 mrun, lrun;
#pragma unroll
  for (int c = 0; c < 4; c++) { mrun[c] = -1e30f; lrun[c] = 0.f; }
  float* myPt = ptbuf + w * 576;

  {
    const u32x4* gA = (const u32x4*)pA + (size_t)cs * 1280;
    const u32x4* gB = (const u32x4*)pB + (size_t)cs * 1216;
    u32x4* sb = (u32x4*)&chunk[0][0];
    for (int idx = tid; idx < 2496; idx += 512)
      sb[idx] = (idx < 1280) ? gA[idx] : gB[idx - 1280];
  }
  __syncthreads();

  int cur = 0;
  for (int ic = 0; ic < nch; ic++) {
    u32x4 pf[5];
    bool havepf = (ic + 1 < nch);
    if (havepf) {
      int ci = cs + ic + 1;
      const u32x4* gA = (const u32x4*)pA + (size_t)ci * 1280;
      const u32x4* gB = (const u32x4*)pB + (size_t)ci * 1216;
#pragma unroll
      for (int i = 0; i < 5; i++) {
        int idx = tid + i * 512;
        if (idx < 2496) pf[i] = (idx < 1280) ? gA[idx] : gB[idx - 1280];
      }
    }
    const bf16x8* bufA = (const bf16x8*)&chunk[cur][0];
    const bf16x8* bufB = (const bf16x8*)&chunk[cur][10240];
    f32x4 L0, L1;
#pragma unroll
    for (int c = 0; c < 4; c++) { L0[c] = 0.f; L1[c] = 0.f; }
#pragma unroll
    for (int kk = 0; kk < 10; kk++) {
      L0 = __builtin_amdgcn_mfma_f32_16x16x32_bf16(afr[kk], bufA[kk * 64 + lane], L0, 0, 0, 0);
      L1 = __builtin_amdgcn_mfma_f32_16x16x32_bf16(afr[kk], bufA[(10 + kk) * 64 + lane], L1, 0, 0, 0);
    }
    f32x4 t;
#pragma unroll
    for (int c = 0; c < 4; c++) t[c] = fmaxf(L0[c], L1[c]);
#pragma unroll
    for (int off = 1; off < 16; off <<= 1) {
      f32x4 o = shflx4(t, off);
#pragma unroll
      for (int c = 0; c < 4; c++) t[c] = fmaxf(t[c], o[c]);
    }
    f32x4 mnew, al, P0v, P1v, rs;
#pragma unroll
    for (int c = 0; c < 4; c++) {
      mnew[c] = fmaxf(mrun[c], t[c]);
      al[c] = __expf(mrun[c] - mnew[c]);
      P0v[c] = __expf(L0[c] - mnew[c]);
      P1v[c] = __expf(L1[c] - mnew[c]);
      rs[c] = P0v[c] + P1v[c];
    }
#pragma unroll
    for (int off = 1; off < 16; off <<= 1) {
      f32x4 o = shflx4(rs, off);
#pragma unroll
      for (int c = 0; c < 4; c++) rs[c] += o[c];
    }
#pragma unroll
    for (int c = 0; c < 4; c++) { lrun[c] = lrun[c] * al[c] + rs[c]; mrun[c] = mnew[c]; }
    // ptbuf is wave-private: same-wave LDS write->read, no block barrier needed.
#pragma unroll
    for (int r = 0; r < 4; r++) {
      myPt[(quad * 4 + r) * 36 + n16] = P0v[r];
      myPt[(quad * 4 + r) * 36 + 16 + n16] = P1v[r];
    }
    f32x4 plo = *(const f32x4*)(myPt + n16 * 36 + quad * 8);
    f32x4 phi = *(const f32x4*)(myPt + n16 * 36 + quad * 8 + 4);
    bf16x8 paf;
#pragma unroll
    for (int c = 0; c < 4; c++) { paf[c] = (__bf16)plo[c]; paf[c + 4] = (__bf16)phi[c]; }
#pragma unroll
    for (int nc = 0; nc < 19; nc++) {
      f32x4 a = acc[nc];
#pragma unroll
      for (int c = 0; c < 4; c++) a[c] *= al[c];
      acc[nc] = __builtin_amdgcn_mfma_f32_16x16x32_bf16(paf, bufB[nc * 64 + lane], a, 0, 0, 0);
    }
    // stage next chunk into the other buffer (no reader conflict this iteration)
    if (havepf) {
      u32x4* sb = (u32x4*)&chunk[cur ^ 1][0];
#pragma unroll
      for (int i = 0; i < 5; i++) {
        int idx = tid + i * 512;
        if (idx < 2496) sb[idx] = pf[i];
      }
    }
    __syncthreads();  // writes to chunk[cur^1] complete; all reads of chunk[cur] done
    cur ^= 1;
  }

  size_t prow = (size_t)sl * 4096 + (size_t)b * 128 + w * 16;
  if (n16 == 0) {
#pragma unroll
    for (int r = 0; r < 4; r++) {
      pML[(prow + quad * 4 + r) * 2 + 0] = mrun[r];
      pML[(prow + quad * 4 + r) * 2 + 1] = lrun[r];
    }
  }
#pragma unroll
  for (int nc = 0; nc < 19; nc++)
#pragma unroll
    for (int r = 0; r < 4; r++)
      pAcc[(prow + quad * 4 + r) * 304 + nc * 16 + n16] = f2bf(acc[nc][r]);
}

// ---------- combine slices + default-embed column -> V bf16 (4096 x 320) ----------
__global__ __launch_bounds__(320) void k_combine(
    const u16* __restrict__ pAcc, const float* __restrict__ pML,
    const u16* __restrict__ X, const u16* __restrict__ de,
    const u16* __restrict__ words, u16* __restrict__ Vout) {
  __shared__ float red[320];
  __shared__ float fs[8];
  __shared__ float sinv, sw;
  int row = blockIdx.x, tid = threadIdx.x;
  float p = 0.f;
  if (tid < 300) p = bf2f(X[(size_t)row * 320 + tid]) * bf2f(de[tid]);
  red[tid] = p;
  __syncthreads();
  if (tid == 0) {
    float d = 0.f;
    for (int i = 0; i < 300; i++) d += red[i];
    float mv[8], lv[8], ms = -1e30f;
    for (int s = 0; s < 8; s++) {
      mv[s] = pML[((size_t)s * 4096 + row) * 2];
      lv[s] = pML[((size_t)s * 4096 + row) * 2 + 1];
      ms = fmaxf(ms, mv[s]);
    }
    float mf = fmaxf(ms, d);
    float pd = __expf(d - mf);
    float l = pd;
    for (int s = 0; s < 8; s++) {
      float f = __expf(mv[s] - mf);
      fs[s] = f;
      l += lv[s] * f;
    }
    sinv = 1.f / l;
    sw = pd / l;
  }
  __syncthreads();
  float v = 0.f;
  if (tid < 300) {
    float a = 0.f;
#pragma unroll
    for (int s = 0; s < 8; s++)
      a += bf2f(pAcc[((size_t)s * 4096 + row) * 304 + tid]) * fs[s];
    v = a * sinv + sw * bf2f(words[(size_t)row * 300 + tid]);
  }
  Vout[(size_t)row * 320 + tid] = f2bf(v);
}

// ---------- xg = V @ lstm_Wih.T + bih + bhh (f32, 4096 x 1200) ----------
__global__ __launch_bounds__(256) void k_xg(const u16* __restrict__ Vb,
                                            const u16* __restrict__ WihT,
                                            const u16* __restrict__ bih,
                                            const u16* __restrict__ bhh,
                                            float* __restrict__ xg) {
  __shared__ float As[300][33];
  int n0 = blockIdx.x * 128;
  int r0 = blockIdx.y * 32;
  int tid = threadIdx.x;
  for (int idx = tid; idx < 32 * 300; idx += 256) {
    int r = idx / 300, k = idx - r * 300;
    As[k][r] = bf2f(Vb[(size_t)(r0 + r) * 320 + k]);
  }
  __syncthreads();
  int j = n0 + (tid & 127);
  if (j >= 1200) return;
  int rh = (tid >> 7) * 16;
  float acc[16];
#pragma unroll
  for (int i = 0; i < 16; i++) acc[i] = 0.f;
  for (int k = 0; k < 300; k++) {
    float bw = bf2f(WihT[(size_t)k * 1200 + j]);
#pragma unroll
    for (int i = 0; i < 16; i++) acc[i] += As[k][rh + i] * bw;
  }
  float bias = bf2f(bih[j]) + bf2f(bhh[j]);
#pragma unroll
  for (int i = 0; i < 16; i++)
    xg[(size_t)(r0 + rh + i) * 1200 + j] = acc[i] + bias;
}

// ---------- lockstep LSTM: 16 blocks, MFMA f16, weights in registers ----------
// Block bid owns dims [d0, d0+nd) x 4 gates (N=80 cols padded). Per step:
// spin(16 seq, acquire) -> load h A-frags (global, f16 A-layout, dbuf) ->
// 20 MFMA/wave -> gl LDS -> activations (c,h in regs) -> publish h slice ->
// barrier -> release seq. h_t for all 32 batches lives in hb[(t+1)&1].
__global__ __launch_bounds__(320, 1) void k_lstm2(
    const float* __restrict__ xg, const u16* __restrict__ pW,
    const int* __restrict__ lengths, u16* __restrict__ hb, u32* __restrict__ seq) {
  __shared__ float gl[32][84];
  __shared__ int s_maxlen;
  int bid = blockIdx.x, tid = threadIdx.x;
  int w = tid >> 6, lane = tid & 63;
  int quad = lane >> 4, n16 = lane & 15;
  int d0 = (bid < 15) ? 19 * bid : 285;
  int nd = (bid < 15) ? 19 : 15;
  {
    int lv = (tid < 32) ? lengths[tid] : 0;
    for (int off2 = 1; off2 < 32; off2 <<= 1) {
      int o = __shfl_xor(lv, off2, 64);
      lv = lv > o ? lv : o;
    }
    if (tid == 0) s_maxlen = lv;
  }
  // B-frags: constant across steps, in registers (wave w = N-tile)
  f16x8 bf[10];
  const u32x4* pw4 = (const u32x4*)(pW + (size_t)bid * 25600);
#pragma unroll
  for (int kt = 0; kt < 10; kt++)
    bf[kt] = __builtin_bit_cast(f16x8, pw4[(w * 10 + kt) * 64 + lane]);
  // activation-thread ownership: items tid and tid+320; item = b*20+dl
  int b0 = tid / 20, dl0 = tid - b0 * 20;
  int b1 = (tid + 320) / 20, dl1 = (tid + 320) - b1 * 20;
  bool a0 = dl0 < nd, a1 = dl1 < nd;
  int len0 = lengths[b0], len1 = lengths[b1];
  int dim0 = d0 + dl0, dim1 = d0 + dl1;
  int sa0 = (((b0 >> 4) * 10 + (dim0 >> 5)) * 64 + ((dim0 >> 3) & 3) * 16 + (b0 & 15)) * 8 + (dim0 & 7);
  int sa1 = (((b1 >> 4) * 10 + (dim1 >> 5)) * 64 + ((dim1 >> 3) & 3) * 16 + (b1 & 15)) * 8 + (dim1 & 7);
  float c0 = 0.f, h0 = 0.f, c1 = 0.f, h1 = 0.f;
  __syncthreads();
  int maxlen = s_maxlen;
  for (int t = 0; t < maxlen; t++) {
    if (tid < 16) {
      while (__hip_atomic_load(&seq[tid * 16], __ATOMIC_ACQUIRE, SCOPE_AGENT) < (u32)t)
        __builtin_amdgcn_s_sleep(2);
    }
    __syncthreads();
    // xv loads (independent of h; overlap with A-frag latency)
    float xv00 = 0.f, xv01 = 0.f, xv02 = 0.f, xv03 = 0.f;
    float xv10 = 0.f, xv11 = 0.f, xv12 = 0.f, xv13 = 0.f;
    const float* xr0 = xg + ((size_t)b0 * 128 + t) * 1200 + dim0;
    const float* xr1 = xg + ((size_t)b1 * 128 + t) * 1200 + dim1;
    if (a0) { xv00 = xr0[0]; xv01 = xr0[300]; xv02 = xr0[600]; xv03 = xr0[900]; }
    if (a1) { xv10 = xr1[0]; xv11 = xr1[300]; xv12 = xr1[600]; xv13 = xr1[900]; }
    // A-frags: h_{t-1} for all 32 batches, f16 A-layout
    const u32x4* hbt = (const u32x4*)hb + (size_t)(t & 1) * 1280;
    u32x4 af[2][10];
#pragma unroll
    for (int mt = 0; mt < 2; mt++)
#pragma unroll
      for (int kt = 0; kt < 10; kt++)
        af[mt][kt] = hbt[(mt * 10 + kt) * 64 + lane];
#pragma unroll
    for (int mt = 0; mt < 2; mt++) {
      f32x4 C;
      C[0] = 0.f; C[1] = 0.f; C[2] = 0.f; C[3] = 0.f;
#pragma unroll
      for (int kt = 0; kt < 10; kt++)
        C = __builtin_amdgcn_mfma_f32_16x16x32_f16(
            __builtin_bit_cast(f16x8, af[mt][kt]), bf[kt], C, 0, 0, 0);
#pragma unroll
      for (int rr = 0; rr < 4; rr++)
        gl[mt * 16 + quad * 4 + rr][w * 16 + n16] = C[rr];
    }
    __syncthreads();
    u16* hbw = hb + (size_t)((t + 1) & 1) * 10240;
    if (a0) {
      float gi = gl[b0][dl0] + xv00, gf = gl[b0][20 + dl0] + xv01;
      float gg = gl[b0][40 + dl0] + xv02, go = gl[b0][60 + dl0] + xv03;
      if (t < len0) {
        c0 = sigm(gf) * c0 + sigm(gi) * tanhf(gg);
        h0 = sigm(go) * tanhf(c0);
      }
      hbw[sa0] = f2h(h0);
    }
    if (a1) {
      float gi = gl[b1][dl1] + xv10, gf = gl[b1][20 + dl1] + xv11;
      float gg = gl[b1][40 + dl1] + xv12, go = gl[b1][60 + dl1] + xv13;
      if (t < len1) {
        c1 = sigm(gf) * c1 + sigm(gi) * tanhf(gg);
        h1 = sigm(go) * tanhf(c1);
      }
      hbw[sa1] = f2h(h1);
    }
    __syncthreads();  // drains vmem stores (vmcnt) block-wide before release
    if (tid == 0)
      __hip_atomic_store(&seq[bid * 16], (u32)(t + 1), __ATOMIC_RELEASE, SCOPE_AGENT);
  }
}

// ---------- RNN tail: q from hb (f16 A-layout), 8 steps h2 = tanh(base + h2@rWhh.T) ----------
__global__ __launch_bounds__(320) void k_rnn(
    const u16* __restrict__ hb, const int* __restrict__ lengths,
    const u16* __restrict__ rWihT, const u16* __restrict__ rWhhT,
    const u16* __restrict__ rbih, const u16* __restrict__ rbhh,
    float* __restrict__ H) {
  __shared__ float qs[304], h2[304], base[304];
  __shared__ int s_maxlen;
  int b = blockIdx.x, tid = threadIdx.x;
  {
    int lv = (tid < 32) ? lengths[tid] : 0;
    for (int off2 = 1; off2 < 32; off2 <<= 1) {
      int o = __shfl_xor(lv, off2, 64);
      lv = lv > o ? lv : o;
    }
    if (tid == 0) s_maxlen = lv;
  }
  __syncthreads();
  int buf = s_maxlen & 1;
  if (tid < 304) {
    float q = 0.f;
    if (tid < 300) {
      int dim = tid;
      int idx = (((b >> 4) * 10 + (dim >> 5)) * 64 + ((dim >> 3) & 3) * 16 + (b & 15)) * 8 + (dim & 7);
      q = h2f(hb[(size_t)buf * 10240 + idx]);
    }
    qs[tid] = q;
    h2[tid] = 0.f;
  }
  __syncthreads();
  if (tid < 300) {
    float a = bf2f(rbih[tid]) + bf2f(rbhh[tid]);
    for (int k = 0; k < 300; k++) a += qs[k] * bf2f(rWihT[(size_t)k * 300 + tid]);
    base[tid] = a;
  }
  __syncthreads();
  for (int s = 0; s < 8; s++) {
    float nv = 0.f;
    if (tid < 300) {
      float a = base[tid];
      for (int k = 0; k < 300; k++) a += h2[k] * bf2f(rWhhT[(size_t)k * 300 + tid]);
      nv = tanhf(a);
    }
    __syncthreads();
    if (tid < 300) {
      h2[tid] = nv;
      H[((size_t)b * 8 + s) * 300 + tid] = nv;
    }
    __syncthreads();
  }
}

// ---------- attention readout ----------
__global__ __launch_bounds__(256) void k_attn(const float* __restrict__ H,
                                              const u16* __restrict__ Vb,
                                              const int* __restrict__ lengths,
                                              const u32* __restrict__ flag,
                                              void* __restrict__ dout) {
  __shared__ float Hs[8][304];
  __shared__ float sc[8][128];
  __shared__ float wsum[8];
  int b = blockIdx.x, tid = threadIdx.x;
  int len = lengths[b];
  int is32 = (int)*flag;
  for (int idx = tid; idx < 8 * 300; idx += 256) {
    int k = idx / 300, j = idx - k * 300;
    Hs[k][j] = H[((size_t)b * 8 + k) * 300 + j];
  }
  __syncthreads();
  for (int s = tid; s < len; s += 256) {
    const u16* vr = Vb + (size_t)(b * 128 + s) * 320;
    float a[8];
#pragma unroll
    for (int k = 0; k < 8; k++) a[k] = 0.f;
    for (int j = 0; j < 300; j++) {
      float v = bf2f(vr[j]);
#pragma unroll
      for (int k = 0; k < 8; k++) a[k] += Hs[k][j] * v;
    }
#pragma unroll
    for (int k = 0; k < 8; k++) sc[k][s] = a[k];
  }
  __syncthreads();
  if (tid < 8) {
    float m = -1e30f;
    for (int s = 0; s < len; s++) m = fmaxf(m, sc[tid][s]);
    float l = 0.f;
    for (int s = 0; s < len; s++) { float e = __expf(sc[tid][s] - m); sc[tid][s] = e; l += e; }
    wsum[tid] = 1.f / l;
  }
  __syncthreads();
  int k = tid >> 5, jl = tid & 31;
  for (int j = jl; j < 300; j += 32) {
    float a = 0.f;
    for (int s = 0; s < len; s++) a += sc[k][s] * bf2f(Vb[(size_t)(b * 128 + s) * 320 + j]);
    float val = a * wsum[k];
    size_t o = ((size_t)b * 8 + k) * 300 + j;
    if (is32) ((float*)dout)[o] = val;
    else ((u16*)dout)[o] = f2bf(val);
  }
}

extern "C" void kernel_launch(void* const* d_in, const int* in_sizes, int n_in,
                              void* d_out, int out_size, void* d_ws, size_t ws_size,
                              hipStream_t stream) {
  (void)in_sizes; (void)n_in; (void)out_size; (void)ws_size;
  const void* words = d_in[0];
  const int* lengths = (const int*)d_in[1];
  const void* vocab = d_in[2];
  const void* de = d_in[3];
  const void* W = d_in[4];
  const void* lWih = d_in[5];
  const void* lWhh = d_in[6];
  const void* lbih = d_in[7];
  const void* lbhh = d_in[8];
  const void* rWih = d_in[9];
  const void* rWhh = d_in[10];
  const void* rbih = d_in[11];
  const void* rbhh = d_in[12];

  char* basep = (char*)d_ws;
  size_t off = 0;
  auto take = [&](size_t bytes) -> char* {
    char* p = basep + off;
    off += (bytes + 255) & ~(size_t)255;
    return p;
  };
  u16* cw    = (u16*)take(1228800 * 2);
  u16* cv    = (u16*)take(6000000 * 2);
  u16* cde   = (u16*)take(300 * 2);
  u16* cW    = (u16*)take(90000 * 2);
  u16* cWih  = (u16*)take(360000 * 2);
  u16* cWhh  = (u16*)take(360000 * 2);
  u16* cbih  = (u16*)take(1200 * 2);
  u16* cbhh  = (u16*)take(1200 * 2);
  u16* crWih = (u16*)take(90000 * 2);
  u16* crWhh = (u16*)take(90000 * 2);
  u16* crbih = (u16*)take(300 * 2);
  u16* crbhh = (u16*)take(300 * 2);
  u32* flag  = (u32*)take(256);
  u16*   X     = (u16*)take((size_t)4096 * 320 * 2);
  u16*   Vb    = (u16*)take((size_t)4096 * 320 * 2);
  u16*   WihT  = (u16*)take((size_t)300 * 1200 * 2);
  u16*   pW4   = (u16*)take((size_t)16 * 25600 * 2);
  u16*   rWihT = (u16*)take((size_t)300 * 300 * 2);
  u16*   rWhhT = (u16*)take((size_t)300 * 300 * 2);
  u16*   pAcc  = (u16*)take((size_t)8 * 4096 * 304 * 2);
  float* pML   = (float*)take((size_t)8 * 4096 * 2 * 4);
  float* H     = (float*)take((size_t)32 * 8 * 300 * 4);
  u16*   hb    = (u16*)take((size_t)2 * 10240 * 2);
  u32*   seq   = (u32*)take((size_t)4096 * 4);
  // union region: pA+pB (dead after k_softmax_v), then xg
  char* ureg = take((size_t)25000192);
  u16*   pA = (u16*)ureg;
  u16*   pB = (u16*)(ureg + (size_t)625 * 10240 * 2);
  float* xg = (float*)ureg;

  k_ingest<<<4096, 256, 0, stream>>>(words, vocab, de, W, lWih, lWhh, lbih, lbhh,
                                     rWih, rWhh, rbih, rbhh,
                                     cw, cv, cde, cW, cWih, cWhh, cbih, cbhh,
                                     crWih, crWhh, crbih, crbhh, flag, seq, (u32*)hb);
  k_transpose_bf<<<dim3(38, 10), 256, 0, stream>>>(cWih, WihT, 1200, 300);
  k_transpose_bf<<<dim3(10, 10), 256, 0, stream>>>(crWih, rWihT, 300, 300);
  k_transpose_bf<<<dim3(10, 10), 256, 0, stream>>>(crWhh, rWhhT, 300, 300);
  k_pack_w4<<<1600, 256, 0, stream>>>(cWhh, pW4);
  k_pack_vocab<<<625, 256, 0, stream>>>(cv, pA, pB);
  k_xw<<<dim3(3, 128), 256, 0, stream>>>(cw, cW, X);
  k_softmax_v<<<256, 512, 0, stream>>>(X, pA, pB, pAcc, pML);
  k_combine<<<4096, 320, 0, stream>>>(pAcc, pML, X, cde, cw, Vb);
  k_xg<<<dim3(10, 128), 256, 0, stream>>>(Vb, WihT, cbih, cbhh, xg);
  k_lstm2<<<16, 320, 0, stream>>>(xg, pW4, lengths, hb, seq);
  k_rnn<<<32, 320, 0, stream>>>(hb, lengths, rWihT, rWhhT, crbih, crbhh, H);
  k_attn<<<32, 256, 0, stream>>>(H, Vb, lengths, flag, d_out);
}

// Round 8
// 1065.263 us; speedup vs baseline: 1.6694x; 1.0084x over previous
//
#include <hip/hip_runtime.h>

// B=32, S=128, D=300 (pad 320), VOCAB=20000 (625 chunks of 32), K=8.
// Inputs may be f32 or bf16 (runtime-detected); canonicalized to bf16 in ws.

typedef unsigned short u16;
typedef unsigned int   u32;
typedef float  f32x4 __attribute__((ext_vector_type(4)));
typedef u32    u32x4 __attribute__((ext_vector_type(4)));
typedef __bf16 bf16x8 __attribute__((ext_vector_type(8)));
typedef _Float16 f16x2 __attribute__((ext_vector_type(2)));
typedef _Float16 f16x8 __attribute__((ext_vector_type(8)));

#define SCOPE_AGENT __HIP_MEMORY_SCOPE_AGENT

__device__ __forceinline__ float bf2f(u16 u) { return __uint_as_float(((u32)u) << 16); }
__device__ __forceinline__ u16 f2bf(float f) {
  u32 x = __float_as_uint(f);
  u32 r = (x + 0x7fffu + ((x >> 16) & 1u)) >> 16;  // RNE
  return (u16)r;
}
__device__ __forceinline__ float sigm(float x) { return 1.f / (1.f + __expf(-x)); }
__device__ __forceinline__ u16 f2h(float f) {
  union { _Float16 h; u16 u; } cv; cv.h = (_Float16)f; return cv.u;
}
__device__ __forceinline__ float h2f(u16 u) {
  union { _Float16 h; u16 u; } cv; cv.u = u; return (float)cv.h;
}

// DPP lane move (VALU-only cross-lane within 16-lane rows)
// 0xB1 = quad_perm xor1, 0x4E = quad_perm xor2, 0x141 = row_half_mirror (xor7
// pairing of quads), 0x140 = row_mirror (xor15 pairing of octets).
template <int CTRL>
__device__ __forceinline__ float dppmv(float v) {
  return __uint_as_float(
      (u32)__builtin_amdgcn_mov_dpp((int)__float_as_uint(v), CTRL, 0xF, 0xF, true));
}

// async global -> LDS stage of one vocab chunk (2496 x 16B); dest is linear
// per-lane (wave-uniform base + lane*16) as required by global_load_lds.
__device__ __forceinline__ void stage_chunk(const u16* __restrict__ pA,
                                            const u16* __restrict__ pB,
                                            int ci, u16* dst, int tid) {
  const u32x4* gA = (const u32x4*)pA + (size_t)ci * 1280;
  const u32x4* gB = (const u32x4*)pB + (size_t)ci * 1216;
  u32x4* sb = (u32x4*)dst;
#pragma unroll
  for (int i = 0; i < 5; i++) {
    int idx = tid + i * 512;
    if (idx < 2496) {
      const u32x4* g = (idx < 1280) ? (gA + idx) : (gB + (idx - 1280));
      __builtin_amdgcn_global_load_lds(
          (const __attribute__((address_space(1))) u32*)(const u32*)g,
          (__attribute__((address_space(3))) u32*)(u32*)(sb + idx), 16, 0, 0);
    }
  }
}

// ---------- ingest: detect f32 vs bf16, canonicalize all float inputs to bf16 ----------
__device__ __forceinline__ void conv_seg(const void* src, u16* dst, int n, int is32,
                                         int t0, int stride) {
  if (is32) {
    const float* s = (const float*)src;
    for (int i = t0; i < n; i += stride) dst[i] = f2bf(s[i]);
  } else {
    const u16* s = (const u16*)src;
    for (int i = t0; i < n; i += stride) dst[i] = s[i];
  }
}

__global__ __launch_bounds__(256) void k_ingest(
    const void* words, const void* vocab, const void* de, const void* W,
    const void* lWih, const void* lWhh, const void* lbih, const void* lbhh,
    const void* rWih, const void* rWhh, const void* rbih, const void* rbhh,
    u16* cw, u16* cv, u16* cde, u16* cW, u16* cWih, u16* cWhh, u16* cbih, u16* cbhh,
    u16* crWih, u16* crWhh, u16* crbih, u16* crbhh, u32* flag, u32* seqz, u32* hbz) {
  __shared__ int s_is32;
  int tid = threadIdx.x;
  int vote = 0;
  if (tid < 64) {
    u32 w = ((const u32*)words)[tid];
    int e = (w >> 7) & 0xFF;  // bf16 low-element exponent field if bf16-packed
    vote = (e >= 100 && e <= 150) ? 1 : 0;
  }
  unsigned long long m = __ballot(vote);
  if (tid == 0) s_is32 = (__popcll(m) < 32) ? 1 : 0;  // few plausible bf16 exps -> f32
  __syncthreads();
  int is32 = s_is32;
  if (blockIdx.x == 0 && tid == 0) *flag = (u32)is32;
  int t0 = blockIdx.x * 256 + tid;
  int stride = gridDim.x * 256;
  if (t0 < 256) seqz[t0] = 0;     // LSTM step counters
  if (t0 < 10240) hbz[t0] = 0;    // LSTM h exchange buffers (f16 A-layout, both bufs)
  conv_seg(words, cw, 1228800, is32, t0, stride);
  conv_seg(vocab, cv, 6000000, is32, t0, stride);
  conv_seg(de, cde, 300, is32, t0, stride);
  conv_seg(W, cW, 90000, is32, t0, stride);
  conv_seg(lWih, cWih, 360000, is32, t0, stride);
  conv_seg(lWhh, cWhh, 360000, is32, t0, stride);
  conv_seg(lbih, cbih, 1200, is32, t0, stride);
  conv_seg(lbhh, cbhh, 1200, is32, t0, stride);
  conv_seg(rWih, crWih, 90000, is32, t0, stride);
  conv_seg(rWhh, crWhh, 90000, is32, t0, stride);
  conv_seg(rbih, crbih, 300, is32, t0, stride);
  conv_seg(rbhh, crbhh, 300, is32, t0, stride);
}

// ---------- transpose bf16 (J x K) -> bf16 (K x J) ----------
__global__ __launch_bounds__(256) void k_transpose_bf(const u16* __restrict__ in,
                                                      u16* __restrict__ out,
                                                      int J, int K) {
  __shared__ u16 t[32][33];
  int j0 = blockIdx.x * 32, k0 = blockIdx.y * 32;
  int lx = threadIdx.x & 31, ly = threadIdx.x >> 5;
  for (int r = ly; r < 32; r += 8) {
    int j = j0 + r, k = k0 + lx;
    t[r][lx] = (j < J && k < K) ? in[(size_t)j * K + k] : (u16)0;
  }
  __syncthreads();
  for (int r = ly; r < 32; r += 8) {
    int k = k0 + r, j = j0 + lx;
    if (k < K && j < J) out[(size_t)k * J + j] = t[lx][r];
  }
}

// ---------- pack lstm_Whh -> per-block MFMA B-frag slices (f16) ----------
// pW[bid=16][(nt*10+kt)*64+lane][8] f16; n = nt*16+(lane&15); gate=n/20; dl=n%20;
// dim = d0(bid)+dl; k = kt*32+(lane>>4)*8+j; val = Whh[gate*300+dim][k] (0 pad).
__global__ __launch_bounds__(256) void k_pack_w4(const u16* __restrict__ Whh,
                                                 u16* __restrict__ pW) {
  int idx = blockIdx.x * 256 + threadIdx.x;
  if (idx >= 16 * 25600) return;
  int bid = idx / 25600, r = idx % 25600;
  int t2 = r >> 9, lane = (r >> 3) & 63, j = r & 7;
  int nt = t2 / 10, kt = t2 % 10;
  int n = nt * 16 + (lane & 15);
  int gate = n / 20, dl = n % 20;
  int d0 = (bid < 15) ? 19 * bid : 285;
  int nd = (bid < 15) ? 19 : 15;
  int k = kt * 32 + ((lane >> 4) * 8) + j;
  u16 out = 0;
  if (dl < nd && k < 300) out = f2h(bf2f(Whh[(size_t)(gate * 300 + d0 + dl) * 300 + k]));
  pW[idx] = out;
}

// ---------- pack vocab into MFMA operand layouts ----------
__global__ __launch_bounds__(256) void k_pack_vocab(const u16* __restrict__ vocab,
                                                    u16* __restrict__ pA,
                                                    u16* __restrict__ pB) {
  __shared__ u16 sv[32][320];
  int ci = blockIdx.x, tid = threadIdx.x;
  for (int idx = tid; idx < 32 * 20; idx += 256) {
    int v = idx / 20, k = 300 + (idx - v * 20);
    sv[v][k] = 0;
  }
  for (int idx = tid; idx < 32 * 300; idx += 256) {
    int v = idx / 300, k = idx - v * 300;
    sv[v][k] = vocab[(size_t)(ci * 32 + v) * 300 + k];
  }
  __syncthreads();
  for (int idx = tid; idx < 10240; idx += 256) {
    int j = idx & 7, lane = (idx >> 3) & 63, t2 = idx >> 9;
    int kk = t2 % 10, h = t2 / 10;
    int v = h * 16 + (lane & 15);
    int k = kk * 32 + ((lane >> 4)) * 8 + j;
    pA[(size_t)ci * 10240 + (size_t)idx] = sv[v][k];
  }
  for (int idx = tid; idx < 9728; idx += 256) {
    int j = idx & 7, lane = (idx >> 3) & 63, nc = idx >> 9;
    int v = (lane >> 4) * 8 + j;
    int n = nc * 16 + (lane & 15);
    pB[(size_t)ci * 9728 + (size_t)idx] = sv[v][n];
  }
}

// ---------- X = words @ W -> bf16 (4096 x 320, zero pad) ----------
__global__ __launch_bounds__(256) void k_xw(const u16* __restrict__ words,
                                            const u16* __restrict__ W,
                                            u16* __restrict__ X) {
  __shared__ float As[300][33];
  int n0 = blockIdx.x * 128;
  int r0 = blockIdx.y * 32;
  int tid = threadIdx.x;
  for (int idx = tid; idx < 32 * 300; idx += 256) {
    int r = idx / 300, k = idx - r * 300;
    As[k][r] = bf2f(words[(size_t)(r0 + r) * 300 + k]);
  }
  __syncthreads();
  int j = n0 + (tid & 127);
  int rh = (tid >> 7) * 16;
  float acc[16];
#pragma unroll
  for (int i = 0; i < 16; i++) acc[i] = 0.f;
  if (j < 300) {
    for (int k = 0; k < 300; k++) {
      float bw = bf2f(W[(size_t)k * 300 + j]);
#pragma unroll
      for (int i = 0; i < 16; i++) acc[i] += As[k][rh + i] * bw;
    }
  }
  if (j < 320) {
#pragma unroll
    for (int i = 0; i < 16; i++) {
      float v = (j < 300) ? acc[i] : 0.f;
      X[(size_t)(r0 + rh + i) * 320 + j] = f2bf(v);
    }
  }
}

// ---------- flash-style softmax-weighted vocab sum (MFMA), per-slice partials ----------
// LDS-pipe relief: (1) 16-lane reductions via DPP (VALU) instead of ds_swizzle
// butterflies -- bit-exact same pairings; (2) chunk staging via global_load_lds
// (async DMA, no ds_write instructions, drained by barrier's vmcnt(0));
// (3) double-buffered chunk, ONE barrier per iteration; ptbuf is wave-private.
__global__ __launch_bounds__(512, 2) void k_softmax_v(
    const u16* __restrict__ X, const u16* __restrict__ pA, const u16* __restrict__ pB,
    u16* __restrict__ pAcc, float* __restrict__ pML) {
  __shared__ __align__(16) u16 chunk[2][19968];
  __shared__ __align__(16) float ptbuf[8 * 576];
  int bid = blockIdx.x;
  int sl = bid & 7, b = bid >> 3;
  int tid = threadIdx.x;
  int w = tid >> 6, lane = tid & 63;
  int quad = lane >> 4, n16 = lane & 15;
  int cs = (sl == 0) ? 0 : 79 + (sl - 1) * 78;
  int nch = (sl == 0) ? 79 : 78;

  int rowA = b * 128 + w * 16 + n16;
  const bf16x8* Xrow = (const bf16x8*)(X + (size_t)rowA * 320);
  bf16x8 afr[10];
#pragma unroll
  for (int kk = 0; kk < 10; kk++) afr[kk] = Xrow[kk * 4 + quad];

  f32x4 acc[19];
#pragma unroll
  for (int i = 0; i < 19; i++) { acc[i][0] = 0.f; acc[i][1] = 0.f; acc[i][2] = 0.f; acc[i][3] = 0.f; }
  f32x4 mrun, lrun;
#pragma unroll
  for (int c = 0; c < 4; c++) { mrun[c] = -1e30f; lrun[c] = 0.f; }
  float* myPt = ptbuf + w * 576;

  stage_chunk(pA, pB, cs, &chunk[0][0], tid);
  __syncthreads();  // barrier implies vmcnt(0): DMA complete

  int cur = 0;
  for (int ic = 0; ic < nch; ic++) {
    if (ic + 1 < nch) stage_chunk(pA, pB, cs + ic + 1, &chunk[cur ^ 1][0], tid);
    const bf16x8* bufA = (const bf16x8*)&chunk[cur][0];
    const bf16x8* bufB = (const bf16x8*)&chunk[cur][10240];
    f32x4 L0, L1;
#pragma unroll
    for (int c = 0; c < 4; c++) { L0[c] = 0.f; L1[c] = 0.f; }
#pragma unroll
    for (int kk = 0; kk < 10; kk++) {
      L0 = __builtin_amdgcn_mfma_f32_16x16x32_bf16(afr[kk], bufA[kk * 64 + lane], L0, 0, 0, 0);
      L1 = __builtin_amdgcn_mfma_f32_16x16x32_bf16(afr[kk], bufA[(10 + kk) * 64 + lane], L1, 0, 0, 0);
    }
    // per-row max over this chunk: DPP reduction over the 16 n16 lanes.
    // xor1,xor2 then quad-pair (xor7-mirror) and octet-pair (xor15-mirror):
    // identical pairings to the xor butterfly -> bit-exact.
    f32x4 t;
#pragma unroll
    for (int c = 0; c < 4; c++) {
      float x = fmaxf(L0[c], L1[c]);
      x = fmaxf(x, dppmv<0xB1>(x));
      x = fmaxf(x, dppmv<0x4E>(x));
      x = fmaxf(x, dppmv<0x141>(x));
      x = fmaxf(x, dppmv<0x140>(x));
      t[c] = x;
    }
    f32x4 mnew, al, P0v, P1v, rs;
#pragma unroll
    for (int c = 0; c < 4; c++) {
      mnew[c] = fmaxf(mrun[c], t[c]);
      al[c] = __expf(mrun[c] - mnew[c]);
      P0v[c] = __expf(L0[c] - mnew[c]);
      P1v[c] = __expf(L1[c] - mnew[c]);
      rs[c] = P0v[c] + P1v[c];
    }
#pragma unroll
    for (int c = 0; c < 4; c++) {
      float x = rs[c];
      x += dppmv<0xB1>(x);
      x += dppmv<0x4E>(x);
      x += dppmv<0x141>(x);
      x += dppmv<0x140>(x);
      rs[c] = x;
    }
#pragma unroll
    for (int c = 0; c < 4; c++) { lrun[c] = lrun[c] * al[c] + rs[c]; mrun[c] = mnew[c]; }
    // ptbuf is wave-private: same-wave LDS write->read, no block barrier needed.
#pragma unroll
    for (int r = 0; r < 4; r++) {
      myPt[(quad * 4 + r) * 36 + n16] = P0v[r];
      myPt[(quad * 4 + r) * 36 + 16 + n16] = P1v[r];
    }
    f32x4 plo = *(const f32x4*)(myPt + n16 * 36 + quad * 8);
    f32x4 phi = *(const f32x4*)(myPt + n16 * 36 + quad * 8 + 4);
    bf16x8 paf;
#pragma unroll
    for (int c = 0; c < 4; c++) { paf[c] = (__bf16)plo[c]; paf[c + 4] = (__bf16)phi[c]; }
#pragma unroll
    for (int nc = 0; nc < 19; nc++) {
      f32x4 a = acc[nc];
#pragma unroll
      for (int c = 0; c < 4; c++) a[c] *= al[c];
      acc[nc] = __builtin_amdgcn_mfma_f32_16x16x32_bf16(paf, bufB[nc * 64 + lane], a, 0, 0, 0);
    }
    __syncthreads();  // drains next-chunk DMA (vmcnt 0) + all reads of chunk[cur]
    cur ^= 1;
  }

  size_t prow = (size_t)sl * 4096 + (size_t)b * 128 + w * 16;
  if (n16 == 0) {
#pragma unroll
    for (int r = 0; r < 4; r++) {
      pML[(prow + quad * 4 + r) * 2 + 0] = mrun[r];
      pML[(prow + quad * 4 + r) * 2 + 1] = lrun[r];
    }
  }
#pragma unroll
  for (int nc = 0; nc < 19; nc++)
#pragma unroll
    for (int r = 0; r < 4; r++)
      pAcc[(prow + quad * 4 + r) * 304 + nc * 16 + n16] = f2bf(acc[nc][r]);
}

// ---------- combine slices + default-embed column -> V bf16 (4096 x 320) ----------
__global__ __launch_bounds__(320) void k_combine(
    const u16* __restrict__ pAcc, const float* __restrict__ pML,
    const u16* __restrict__ X, const u16* __restrict__ de,
    const u16* __restrict__ words, u16* __restrict__ Vout) {
  __shared__ float red[320];
  __shared__ float fs[8];
  __shared__ float sinv, sw;
  int row = blockIdx.x, tid = threadIdx.x;
  float p = 0.f;
  if (tid < 300) p = bf2f(X[(size_t)row * 320 + tid]) * bf2f(de[tid]);
  red[tid] = p;
  __syncthreads();
  if (tid == 0) {
    float d = 0.f;
    for (int i = 0; i < 300; i++) d += red[i];
    float mv[8], lv[8], ms = -1e30f;
    for (int s = 0; s < 8; s++) {
      mv[s] = pML[((size_t)s * 4096 + row) * 2];
      lv[s] = pML[((size_t)s * 4096 + row) * 2 + 1];
      ms = fmaxf(ms, mv[s]);
    }
    float mf = fmaxf(ms, d);
    float pd = __expf(d - mf);
    float l = pd;
    for (int s = 0; s < 8; s++) {
      float f = __expf(mv[s] - mf);
      fs[s] = f;
      l += lv[s] * f;
    }
    sinv = 1.f / l;
    sw = pd / l;
  }
  __syncthreads();
  float v = 0.f;
  if (tid < 300) {
    float a = 0.f;
#pragma unroll
    for (int s = 0; s < 8; s++)
      a += bf2f(pAcc[((size_t)s * 4096 + row) * 304 + tid]) * fs[s];
    v = a * sinv + sw * bf2f(words[(size_t)row * 300 + tid]);
  }
  Vout[(size_t)row * 320 + tid] = f2bf(v);
}

// ---------- xg = V @ lstm_Wih.T + bih + bhh (f32, 4096 x 1200) ----------
__global__ __launch_bounds__(256) void k_xg(const u16* __restrict__ Vb,
                                            const u16* __restrict__ WihT,
                                            const u16* __restrict__ bih,
                                            const u16* __restrict__ bhh,
                                            float* __restrict__ xg) {
  __shared__ float As[300][33];
  int n0 = blockIdx.x * 128;
  int r0 = blockIdx.y * 32;
  int tid = threadIdx.x;
  for (int idx = tid; idx < 32 * 300; idx += 256) {
    int r = idx / 300, k = idx - r * 300;
    As[k][r] = bf2f(Vb[(size_t)(r0 + r) * 320 + k]);
  }
  __syncthreads();
  int j = n0 + (tid & 127);
  if (j >= 1200) return;
  int rh = (tid >> 7) * 16;
  float acc[16];
#pragma unroll
  for (int i = 0; i < 16; i++) acc[i] = 0.f;
  for (int k = 0; k < 300; k++) {
    float bw = bf2f(WihT[(size_t)k * 1200 + j]);
#pragma unroll
    for (int i = 0; i < 16; i++) acc[i] += As[k][rh + i] * bw;
  }
  float bias = bf2f(bih[j]) + bf2f(bhh[j]);
#pragma unroll
  for (int i = 0; i < 16; i++)
    xg[(size_t)(r0 + rh + i) * 1200 + j] = acc[i] + bias;
}

// ---------- lockstep LSTM: 16 blocks, MFMA f16, weights in registers ----------
// Block bid owns dims [d0, d0+nd) x 4 gates (N=80 cols padded). Per step:
// spin(16 seq, acquire) -> load h A-frags (global, f16 A-layout, dbuf) ->
// 20 MFMA/wave -> gl LDS -> activations (c,h in regs) -> publish h slice ->
// barrier -> release seq. h_t for all 32 batches lives in hb[(t+1)&1].
__global__ __launch_bounds__(320, 1) void k_lstm2(
    const float* __restrict__ xg, const u16* __restrict__ pW,
    const int* __restrict__ lengths, u16* __restrict__ hb, u32* __restrict__ seq) {
  __shared__ float gl[32][84];
  __shared__ int s_maxlen;
  int bid = blockIdx.x, tid = threadIdx.x;
  int w = tid >> 6, lane = tid & 63;
  int quad = lane >> 4, n16 = lane & 15;
  int d0 = (bid < 15) ? 19 * bid : 285;
  int nd = (bid < 15) ? 19 : 15;
  {
    int lv = (tid < 32) ? lengths[tid] : 0;
    for (int off2 = 1; off2 < 32; off2 <<= 1) {
      int o = __shfl_xor(lv, off2, 64);
      lv = lv > o ? lv : o;
    }
    if (tid == 0) s_maxlen = lv;
  }
  // B-frags: constant across steps, in registers (wave w = N-tile)
  f16x8 bf[10];
  const u32x4* pw4 = (const u32x4*)(pW + (size_t)bid * 25600);
#pragma unroll
  for (int kt = 0; kt < 10; kt++)
    bf[kt] = __builtin_bit_cast(f16x8, pw4[(w * 10 + kt) * 64 + lane]);
  // activation-thread ownership: items tid and tid+320; item = b*20+dl
  int b0 = tid / 20, dl0 = tid - b0 * 20;
  int b1 = (tid + 320) / 20, dl1 = (tid + 320) - b1 * 20;
  bool a0 = dl0 < nd, a1 = dl1 < nd;
  int len0 = lengths[b0], len1 = lengths[b1];
  int dim0 = d0 + dl0, dim1 = d0 + dl1;
  int sa0 = (((b0 >> 4) * 10 + (dim0 >> 5)) * 64 + ((dim0 >> 3) & 3) * 16 + (b0 & 15)) * 8 + (dim0 & 7);
  int sa1 = (((b1 >> 4) * 10 + (dim1 >> 5)) * 64 + ((dim1 >> 3) & 3) * 16 + (b1 & 15)) * 8 + (dim1 & 7);
  float c0 = 0.f, h0 = 0.f, c1 = 0.f, h1 = 0.f;
  __syncthreads();
  int maxlen = s_maxlen;
  for (int t = 0; t < maxlen; t++) {
    if (tid < 16) {
      while (__hip_atomic_load(&seq[tid * 16], __ATOMIC_ACQUIRE, SCOPE_AGENT) < (u32)t)
        __builtin_amdgcn_s_sleep(2);
    }
    __syncthreads();
    // xv loads (independent of h; overlap with A-frag latency)
    float xv00 = 0.f, xv01 = 0.f, xv02 = 0.f, xv03 = 0.f;
    float xv10 = 0.f, xv11 = 0.f, xv12 = 0.f, xv13 = 0.f;
    const float* xr0 = xg + ((size_t)b0 * 128 + t) * 1200 + dim0;
    const float* xr1 = xg + ((size_t)b1 * 128 + t) * 1200 + dim1;
    if (a0) { xv00 = xr0[0]; xv01 = xr0[300]; xv02 = xr0[600]; xv03 = xr0[900]; }
    if (a1) { xv10 = xr1[0]; xv11 = xr1[300]; xv12 = xr1[600]; xv13 = xr1[900]; }
    // A-frags: h_{t-1} for all 32 batches, f16 A-layout
    const u32x4* hbt = (const u32x4*)hb + (size_t)(t & 1) * 1280;
    u32x4 af[2][10];
#pragma unroll
    for (int mt = 0; mt < 2; mt++)
#pragma unroll
      for (int kt = 0; kt < 10; kt++)
        af[mt][kt] = hbt[(mt * 10 + kt) * 64 + lane];
#pragma unroll
    for (int mt = 0; mt < 2; mt++) {
      f32x4 C;
      C[0] = 0.f; C[1] = 0.f; C[2] = 0.f; C[3] = 0.f;
#pragma unroll
      for (int kt = 0; kt < 10; kt++)
        C = __builtin_amdgcn_mfma_f32_16x16x32_f16(
            __builtin_bit_cast(f16x8, af[mt][kt]), bf[kt], C, 0, 0, 0);
#pragma unroll
      for (int rr = 0; rr < 4; rr++)
        gl[mt * 16 + quad * 4 + rr][w * 16 + n16] = C[rr];
    }
    __syncthreads();
    u16* hbw = hb + (size_t)((t + 1) & 1) * 10240;
    if (a0) {
      float gi = gl[b0][dl0] + xv00, gf = gl[b0][20 + dl0] + xv01;
      float gg = gl[b0][40 + dl0] + xv02, go = gl[b0][60 + dl0] + xv03;
      if (t < len0) {
        c0 = sigm(gf) * c0 + sigm(gi) * tanhf(gg);
        h0 = sigm(go) * tanhf(c0);
      }
      hbw[sa0] = f2h(h0);
    }
    if (a1) {
      float gi = gl[b1][dl1] + xv10, gf = gl[b1][20 + dl1] + xv11;
      float gg = gl[b1][40 + dl1] + xv12, go = gl[b1][60 + dl1] + xv13;
      if (t < len1) {
        c1 = sigm(gf) * c1 + sigm(gi) * tanhf(gg);
        h1 = sigm(go) * tanhf(c1);
      }
      hbw[sa1] = f2h(h1);
    }
    __syncthreads();  // drains vmem stores (vmcnt) block-wide before release
    if (tid == 0)
      __hip_atomic_store(&seq[bid * 16], (u32)(t + 1), __ATOMIC_RELEASE, SCOPE_AGENT);
  }
}

// ---------- RNN tail: q from hb (f16 A-layout), 8 steps h2 = tanh(base + h2@rWhh.T) ----------
__global__ __launch_bounds__(320) void k_rnn(
    const u16* __restrict__ hb, const int* __restrict__ lengths,
    const u16* __restrict__ rWihT, const u16* __restrict__ rWhhT,
    const u16* __restrict__ rbih, const u16* __restrict__ rbhh,
    float* __restrict__ H) {
  __shared__ float qs[304], h2[304], base[304];
  __shared__ int s_maxlen;
  int b = blockIdx.x, tid = threadIdx.x;
  {
    int lv = (tid < 32) ? lengths[tid] : 0;
    for (int off2 = 1; off2 < 32; off2 <<= 1) {
      int o = __shfl_xor(lv, off2, 64);
      lv = lv > o ? lv : o;
    }
    if (tid == 0) s_maxlen = lv;
  }
  __syncthreads();
  int buf = s_maxlen & 1;
  if (tid < 304) {
    float q = 0.f;
    if (tid < 300) {
      int dim = tid;
      int idx = (((b >> 4) * 10 + (dim >> 5)) * 64 + ((dim >> 3) & 3) * 16 + (b & 15)) * 8 + (dim & 7);
      q = h2f(hb[(size_t)buf * 10240 + idx]);
    }
    qs[tid] = q;
    h2[tid] = 0.f;
  }
  __syncthreads();
  if (tid < 300) {
    float a = bf2f(rbih[tid]) + bf2f(rbhh[tid]);
    for (int k = 0; k < 300; k++) a += qs[k] * bf2f(rWihT[(size_t)k * 300 + tid]);
    base[tid] = a;
  }
  __syncthreads();
  for (int s = 0; s < 8; s++) {
    float nv = 0.f;
    if (tid < 300) {
      float a = base[tid];
      for (int k = 0; k < 300; k++) a += h2[k] * bf2f(rWhhT[(size_t)k * 300 + tid]);
      nv = tanhf(a);
    }
    __syncthreads();
    if (tid < 300) {
      h2[tid] = nv;
      H[((size_t)b * 8 + s) * 300 + tid] = nv;
    }
    __syncthreads();
  }
}

// ---------- attention readout ----------
__global__ __launch_bounds__(256) void k_attn(const float* __restrict__ H,
                                              const u16* __restrict__ Vb,
                                              const int* __restrict__ lengths,
                                              const u32* __restrict__ flag,
                                              void* __restrict__ dout) {
  __shared__ float Hs[8][304];
  __shared__ float sc[8][128];
  __shared__ float wsum[8];
  int b = blockIdx.x, tid = threadIdx.x;
  int len = lengths[b];
  int is32 = (int)*flag;
  for (int idx = tid; idx < 8 * 300; idx += 256) {
    int k = idx / 300, j = idx - k * 300;
    Hs[k][j] = H[((size_t)b * 8 + k) * 300 + j];
  }
  __syncthreads();
  for (int s = tid; s < len; s += 256) {
    const u16* vr = Vb + (size_t)(b * 128 + s) * 320;
    float a[8];
#pragma unroll
    for (int k = 0; k < 8; k++) a[k] = 0.f;
    for (int j = 0; j < 300; j++) {
      float v = bf2f(vr[j]);
#pragma unroll
      for (int k = 0; k < 8; k++) a[k] += Hs[k][j] * v;
    }
#pragma unroll
    for (int k = 0; k < 8; k++) sc[k][s] = a[k];
  }
  __syncthreads();
  if (tid < 8) {
    float m = -1e30f;
    for (int s = 0; s < len; s++) m = fmaxf(m, sc[tid][s]);
    float l = 0.f;
    for (int s = 0; s < len; s++) { float e = __expf(sc[tid][s] - m); sc[tid][s] = e; l += e; }
    wsum[tid] = 1.f / l;
  }
  __syncthreads();
  int k = tid >> 5, jl = tid & 31;
  for (int j = jl; j < 300; j += 32) {
    float a = 0.f;
    for (int s = 0; s < len; s++) a += sc[k][s] * bf2f(Vb[(size_t)(b * 128 + s) * 320 + j]);
    float val = a * wsum[k];
    size_t o = ((size_t)b * 8 + k) * 300 + j;
    if (is32) ((float*)dout)[o] = val;
    else ((u16*)dout)[o] = f2bf(val);
  }
}

extern "C" void kernel_launch(void* const* d_in, const int* in_sizes, int n_in,
                              void* d_out, int out_size, void* d_ws, size_t ws_size,
                              hipStream_t stream) {
  (void)in_sizes; (void)n_in; (void)out_size; (void)ws_size;
  const void* words = d_in[0];
  const int* lengths = (const int*)d_in[1];
  const void* vocab = d_in[2];
  const void* de = d_in[3];
  const void* W = d_in[4];
  const void* lWih = d_in[5];
  const void* lWhh = d_in[6];
  const void* lbih = d_in[7];
  const void* lbhh = d_in[8];
  const void* rWih = d_in[9];
  const void* rWhh = d_in[10];
  const void* rbih = d_in[11];
  const void* rbhh = d_in[12];

  char* basep = (char*)d_ws;
  size_t off = 0;
  auto take = [&](size_t bytes) -> char* {
    char* p = basep + off;
    off += (bytes + 255) & ~(size_t)255;
    return p;
  };
  u16* cw    = (u16*)take(1228800 * 2);
  u16* cv    = (u16*)take(6000000 * 2);
  u16* cde   = (u16*)take(300 * 2);
  u16* cW    = (u16*)take(90000 * 2);
  u16* cWih  = (u16*)take(360000 * 2);
  u16* cWhh  = (u16*)take(360000 * 2);
  u16* cbih  = (u16*)take(1200 * 2);
  u16* cbhh  = (u16*)take(1200 * 2);
  u16* crWih = (u16*)take(90000 * 2);
  u16* crWhh = (u16*)take(90000 * 2);
  u16* crbih = (u16*)take(300 * 2);
  u16* crbhh = (u16*)take(300 * 2);
  u32* flag  = (u32*)take(256);
  u16*   X     = (u16*)take((size_t)4096 * 320 * 2);
  u16*   Vb    = (u16*)take((size_t)4096 * 320 * 2);
  u16*   WihT  = (u16*)take((size_t)300 * 1200 * 2);
  u16*   pW4   = (u16*)take((size_t)16 * 25600 * 2);
  u16*   rWihT = (u16*)take((size_t)300 * 300 * 2);
  u16*   rWhhT = (u16*)take((size_t)300 * 300 * 2);
  u16*   pAcc  = (u16*)take((size_t)8 * 4096 * 304 * 2);
  float* pML   = (float*)take((size_t)8 * 4096 * 2 * 4);
  float* H     = (float*)take((size_t)32 * 8 * 300 * 4);
  u16*   hb    = (u16*)take((size_t)2 * 10240 * 2);
  u32*   seq   = (u32*)take((size_t)4096 * 4);
  // union region: pA+pB (dead after k_softmax_v), then xg
  char* ureg = take((size_t)25000192);
  u16*   pA = (u16*)ureg;
  u16*   pB = (u16*)(ureg + (size_t)625 * 10240 * 2);
  float* xg = (float*)ureg;

  k_ingest<<<4096, 256, 0, stream>>>(words, vocab, de, W, lWih, lWhh, lbih, lbhh,
                                     rWih, rWhh, rbih, rbhh,
                                     cw, cv, cde, cW, cWih, cWhh, cbih, cbhh,
                                     crWih, crWhh, crbih, crbhh, flag, seq, (u32*)hb);
  k_transpose_bf<<<dim3(38, 10), 256, 0, stream>>>(cWih, WihT, 1200, 300);
  k_transpose_bf<<<dim3(10, 10), 256, 0, stream>>>(crWih, rWihT, 300, 300);
  k_transpose_bf<<<dim3(10, 10), 256, 0, stream>>>(crWhh, rWhhT, 300, 300);
  k_pack_w4<<<1600, 256, 0, stream>>>(cWhh, pW4);
  k_pack_vocab<<<625, 256, 0, stream>>>(cv, pA, pB);
  k_xw<<<dim3(3, 128), 256, 0, stream>>>(cw, cW, X);
  k_softmax_v<<<256, 512, 0, stream>>>(X, pA, pB, pAcc, pML);
  k_combine<<<4096, 320, 0, stream>>>(pAcc, pML, X, cde, cw, Vb);
  k_xg<<<dim3(10, 128), 256, 0, stream>>>(Vb, WihT, cbih, cbhh, xg);
  k_lstm2<<<16, 320, 0, stream>>>(xg, pW4, lengths, hb, seq);
  k_rnn<<<32, 320, 0, stream>>>(hb, lengths, rWihT, rWhhT, crbih, crbhh, H);
  k_attn<<<32, 256, 0, stream>>>(H, Vb, lengths, flag, d_out);
}

// Round 9
// 990.572 us; speedup vs baseline: 1.7953x; 1.0754x over previous
//
#include <hip/hip_runtime.h>

// B=32, S=128, D=300 (pad 320), VOCAB=20000 (625 chunks of 32), K=8.
// Inputs may be f32 or bf16 (runtime-detected); canonicalized to bf16 in ws.

typedef unsigned short u16;
typedef unsigned int   u32;
typedef float  f32x4 __attribute__((ext_vector_type(4)));
typedef u32    u32x4 __attribute__((ext_vector_type(4)));
typedef __bf16 bf16x8 __attribute__((ext_vector_type(8)));
typedef _Float16 f16x2 __attribute__((ext_vector_type(2)));
typedef _Float16 f16x8 __attribute__((ext_vector_type(8)));

#define SCOPE_AGENT __HIP_MEMORY_SCOPE_AGENT

__device__ __forceinline__ float bf2f(u16 u) { return __uint_as_float(((u32)u) << 16); }
__device__ __forceinline__ u16 f2bf(float f) {
  u32 x = __float_as_uint(f);
  u32 r = (x + 0x7fffu + ((x >> 16) & 1u)) >> 16;  // RNE
  return (u16)r;
}
__device__ __forceinline__ float sigm(float x) { return 1.f / (1.f + __expf(-x)); }
__device__ __forceinline__ u16 f2h(float f) {
  union { _Float16 h; u16 u; } cv; cv.h = (_Float16)f; return cv.u;
}
__device__ __forceinline__ float h2f(u16 u) {
  union { _Float16 h; u16 u; } cv; cv.u = u; return (float)cv.h;
}

// DPP lane move (VALU-only cross-lane within 16-lane rows)
template <int CTRL>
__device__ __forceinline__ float dppmv(float v) {
  return __uint_as_float(
      (u32)__builtin_amdgcn_mov_dpp((int)__float_as_uint(v), CTRL, 0xF, 0xF, true));
}

// async global -> LDS stage of one vocab chunk (2496 x 16B)
__device__ __forceinline__ void stage_chunk(const u16* __restrict__ pA,
                                            const u16* __restrict__ pB,
                                            int ci, u16* dst, int tid) {
  const u32x4* gA = (const u32x4*)pA + (size_t)ci * 1280;
  const u32x4* gB = (const u32x4*)pB + (size_t)ci * 1216;
  u32x4* sb = (u32x4*)dst;
#pragma unroll
  for (int i = 0; i < 5; i++) {
    int idx = tid + i * 512;
    if (idx < 2496) {
      const u32x4* g = (idx < 1280) ? (gA + idx) : (gB + (idx - 1280));
      __builtin_amdgcn_global_load_lds(
          (const __attribute__((address_space(1))) u32*)(const u32*)g,
          (__attribute__((address_space(3))) u32*)(u32*)(sb + idx), 16, 0, 0);
    }
  }
}

// ---------- ingest: detect f32 vs bf16, canonicalize all float inputs to bf16 ----------
__device__ __forceinline__ void conv_seg(const void* src, u16* dst, int n, int is32,
                                         int t0, int stride) {
  if (is32) {
    const float* s = (const float*)src;
    for (int i = t0; i < n; i += stride) dst[i] = f2bf(s[i]);
  } else {
    const u16* s = (const u16*)src;
    for (int i = t0; i < n; i += stride) dst[i] = s[i];
  }
}

__global__ __launch_bounds__(256) void k_ingest(
    const void* words, const void* vocab, const void* de, const void* W,
    const void* lWih, const void* lWhh, const void* lbih, const void* lbhh,
    const void* rWih, const void* rWhh, const void* rbih, const void* rbhh,
    u16* cw, u16* cv, u16* cde, u16* cW, u16* cWih, u16* cWhh, u16* cbih, u16* cbhh,
    u16* crWih, u16* crWhh, u16* crbih, u16* crbhh, u32* flag, u32* seqz, u32* hbz) {
  __shared__ int s_is32;
  int tid = threadIdx.x;
  int vote = 0;
  if (tid < 64) {
    u32 w = ((const u32*)words)[tid];
    int e = (w >> 7) & 0xFF;  // bf16 low-element exponent field if bf16-packed
    vote = (e >= 100 && e <= 150) ? 1 : 0;
  }
  unsigned long long m = __ballot(vote);
  if (tid == 0) s_is32 = (__popcll(m) < 32) ? 1 : 0;  // few plausible bf16 exps -> f32
  __syncthreads();
  int is32 = s_is32;
  if (blockIdx.x == 0 && tid == 0) *flag = (u32)is32;
  int t0 = blockIdx.x * 256 + tid;
  int stride = gridDim.x * 256;
  if (t0 < 256) seqz[t0] = 0;     // LSTM step counters (16 flags x stride 16)
  if (t0 < 10240) hbz[t0] = 0;    // LSTM h exchange: 2 cliques x 2 bufs x 5120 u16
  conv_seg(words, cw, 1228800, is32, t0, stride);
  conv_seg(vocab, cv, 6000000, is32, t0, stride);
  conv_seg(de, cde, 300, is32, t0, stride);
  conv_seg(W, cW, 90000, is32, t0, stride);
  conv_seg(lWih, cWih, 360000, is32, t0, stride);
  conv_seg(lWhh, cWhh, 360000, is32, t0, stride);
  conv_seg(lbih, cbih, 1200, is32, t0, stride);
  conv_seg(lbhh, cbhh, 1200, is32, t0, stride);
  conv_seg(rWih, crWih, 90000, is32, t0, stride);
  conv_seg(rWhh, crWhh, 90000, is32, t0, stride);
  conv_seg(rbih, crbih, 300, is32, t0, stride);
  conv_seg(rbhh, crbhh, 300, is32, t0, stride);
}

// ---------- transpose bf16 (J x K) -> bf16 (K x J) ----------
__global__ __launch_bounds__(256) void k_transpose_bf(const u16* __restrict__ in,
                                                      u16* __restrict__ out,
                                                      int J, int K) {
  __shared__ u16 t[32][33];
  int j0 = blockIdx.x * 32, k0 = blockIdx.y * 32;
  int lx = threadIdx.x & 31, ly = threadIdx.x >> 5;
  for (int r = ly; r < 32; r += 8) {
    int j = j0 + r, k = k0 + lx;
    t[r][lx] = (j < J && k < K) ? in[(size_t)j * K + k] : (u16)0;
  }
  __syncthreads();
  for (int r = ly; r < 32; r += 8) {
    int k = k0 + r, j = j0 + lx;
    if (k < K && j < J) out[(size_t)k * J + j] = t[lx][r];
  }
}

// ---------- pack lstm_Whh -> per-dim-block MFMA B-frag slices (f16) ----------
// Block bid owns dims [38*bid, 38*bid+nd) (nd=38, last 34); cols n = gate*40+dl (160).
// Layout: pW[bid*51200 + ((w*10+kt)*64 + lane)*8 + j] f16; wave-tile w = n>>4.
// n = w*16 + (lane&15); gate = n/40; dl = n%40; dim = 38*bid+dl;
// k = kt*32 + (lane>>4)*8 + j; val = Whh[gate*300+dim][k] (0 if dl>=nd or k>=300).
// (verified refcheck in round 5 / k_lstm5)
__global__ __launch_bounds__(256) void k_pack_w8(const u16* __restrict__ Whh,
                                                 u16* __restrict__ pW) {
  int idx = blockIdx.x * 256 + threadIdx.x;
  if (idx >= 409600) return;
  int bid = idx / 51200;
  int r = idx - bid * 51200;
  int j = r & 7;
  int lane = (r >> 3) & 63;
  int t2 = r >> 9;           // 0..99 = w*10 + kt
  int kt = t2 % 10, w = t2 / 10;
  int n16 = lane & 15, quad = lane >> 4;
  int n = w * 16 + n16;
  int gate = n / 40, dl = n - gate * 40;
  int nd = (bid < 7) ? 38 : 34;
  int dim = 38 * bid + dl;
  int k = kt * 32 + quad * 8 + j;
  u16 out = 0;
  if (dl < nd && k < 300)
    out = f2h(bf2f(Whh[(size_t)(gate * 300 + dim) * 300 + k]));
  pW[idx] = out;
}

// ---------- pack vocab into MFMA operand layouts ----------
__global__ __launch_bounds__(256) void k_pack_vocab(const u16* __restrict__ vocab,
                                                    u16* __restrict__ pA,
                                                    u16* __restrict__ pB) {
  __shared__ u16 sv[32][320];
  int ci = blockIdx.x, tid = threadIdx.x;
  for (int idx = tid; idx < 32 * 20; idx += 256) {
    int v = idx / 20, k = 300 + (idx - v * 20);
    sv[v][k] = 0;
  }
  for (int idx = tid; idx < 32 * 300; idx += 256) {
    int v = idx / 300, k = idx - v * 300;
    sv[v][k] = vocab[(size_t)(ci * 32 + v) * 300 + k];
  }
  __syncthreads();
  for (int idx = tid; idx < 10240; idx += 256) {
    int j = idx & 7, lane = (idx >> 3) & 63, t2 = idx >> 9;
    int kk = t2 % 10, h = t2 / 10;
    int v = h * 16 + (lane & 15);
    int k = kk * 32 + ((lane >> 4)) * 8 + j;
    pA[(size_t)ci * 10240 + (size_t)idx] = sv[v][k];
  }
  for (int idx = tid; idx < 9728; idx += 256) {
    int j = idx & 7, lane = (idx >> 3) & 63, nc = idx >> 9;
    int v = (lane >> 4) * 8 + j;
    int n = nc * 16 + (lane & 15);
    pB[(size_t)ci * 9728 + (size_t)idx] = sv[v][n];
  }
}

// ---------- X = words @ W -> bf16 (4096 x 320, zero pad) ----------
__global__ __launch_bounds__(256) void k_xw(const u16* __restrict__ words,
                                            const u16* __restrict__ W,
                                            u16* __restrict__ X) {
  __shared__ float As[300][33];
  int n0 = blockIdx.x * 128;
  int r0 = blockIdx.y * 32;
  int tid = threadIdx.x;
  for (int idx = tid; idx < 32 * 300; idx += 256) {
    int r = idx / 300, k = idx - r * 300;
    As[k][r] = bf2f(words[(size_t)(r0 + r) * 300 + k]);
  }
  __syncthreads();
  int j = n0 + (tid & 127);
  int rh = (tid >> 7) * 16;
  float acc[16];
#pragma unroll
  for (int i = 0; i < 16; i++) acc[i] = 0.f;
  if (j < 300) {
    for (int k = 0; k < 300; k++) {
      float bw = bf2f(W[(size_t)k * 300 + j]);
#pragma unroll
      for (int i = 0; i < 16; i++) acc[i] += As[k][rh + i] * bw;
    }
  }
  if (j < 320) {
#pragma unroll
    for (int i = 0; i < 16; i++) {
      float v = (j < 300) ? acc[i] : 0.f;
      X[(size_t)(r0 + rh + i) * 320 + j] = f2bf(v);
    }
  }
}

// ---------- flash-style softmax-weighted vocab sum (MFMA), per-slice partials ----------
__global__ __launch_bounds__(512, 2) void k_softmax_v(
    const u16* __restrict__ X, const u16* __restrict__ pA, const u16* __restrict__ pB,
    u16* __restrict__ pAcc, float* __restrict__ pML) {
  __shared__ __align__(16) u16 chunk[2][19968];
  __shared__ __align__(16) float ptbuf[8 * 576];
  int bid = blockIdx.x;
  int sl = bid & 7, b = bid >> 3;
  int tid = threadIdx.x;
  int w = tid >> 6, lane = tid & 63;
  int quad = lane >> 4, n16 = lane & 15;
  int cs = (sl == 0) ? 0 : 79 + (sl - 1) * 78;
  int nch = (sl == 0) ? 79 : 78;

  int rowA = b * 128 + w * 16 + n16;
  const bf16x8* Xrow = (const bf16x8*)(X + (size_t)rowA * 320);
  bf16x8 afr[10];
#pragma unroll
  for (int kk = 0; kk < 10; kk++) afr[kk] = Xrow[kk * 4 + quad];

  f32x4 acc[19];
#pragma unroll
  for (int i = 0; i < 19; i++) { acc[i][0] = 0.f; acc[i][1] = 0.f; acc[i][2] = 0.f; acc[i][3] = 0.f; }
  f32x4 mrun, lrun;
#pragma unroll
  for (int c = 0; c < 4; c++) { mrun[c] = -1e30f; lrun[c] = 0.f; }
  float* myPt = ptbuf + w * 576;

  stage_chunk(pA, pB, cs, &chunk[0][0], tid);
  __syncthreads();  // barrier implies vmcnt(0): DMA complete

  int cur = 0;
  for (int ic = 0; ic < nch; ic++) {
    if (ic + 1 < nch) stage_chunk(pA, pB, cs + ic + 1, &chunk[cur ^ 1][0], tid);
    const bf16x8* bufA = (const bf16x8*)&chunk[cur][0];
    const bf16x8* bufB = (const bf16x8*)&chunk[cur][10240];
    f32x4 L0, L1;
#pragma unroll
    for (int c = 0; c < 4; c++) { L0[c] = 0.f; L1[c] = 0.f; }
#pragma unroll
    for (int kk = 0; kk < 10; kk++) {
      L0 = __builtin_amdgcn_mfma_f32_16x16x32_bf16(afr[kk], bufA[kk * 64 + lane], L0, 0, 0, 0);
      L1 = __builtin_amdgcn_mfma_f32_16x16x32_bf16(afr[kk], bufA[(10 + kk) * 64 + lane], L1, 0, 0, 0);
    }
    f32x4 t;
#pragma unroll
    for (int c = 0; c < 4; c++) {
      float x = fmaxf(L0[c], L1[c]);
      x = fmaxf(x, dppmv<0xB1>(x));
      x = fmaxf(x, dppmv<0x4E>(x));
      x = fmaxf(x, dppmv<0x141>(x));
      x = fmaxf(x, dppmv<0x140>(x));
      t[c] = x;
    }
    f32x4 mnew, al, P0v, P1v, rs;
#pragma unroll
    for (int c = 0; c < 4; c++) {
      mnew[c] = fmaxf(mrun[c], t[c]);
      al[c] = __expf(mrun[c] - mnew[c]);
      P0v[c] = __expf(L0[c] - mnew[c]);
      P1v[c] = __expf(L1[c] - mnew[c]);
      rs[c] = P0v[c] + P1v[c];
    }
#pragma unroll
    for (int c = 0; c < 4; c++) {
      float x = rs[c];
      x += dppmv<0xB1>(x);
      x += dppmv<0x4E>(x);
      x += dppmv<0x141>(x);
      x += dppmv<0x140>(x);
      rs[c] = x;
    }
#pragma unroll
    for (int c = 0; c < 4; c++) { lrun[c] = lrun[c] * al[c] + rs[c]; mrun[c] = mnew[c]; }
#pragma unroll
    for (int r = 0; r < 4; r++) {
      myPt[(quad * 4 + r) * 36 + n16] = P0v[r];
      myPt[(quad * 4 + r) * 36 + 16 + n16] = P1v[r];
    }
    f32x4 plo = *(const f32x4*)(myPt + n16 * 36 + quad * 8);
    f32x4 phi = *(const f32x4*)(myPt + n16 * 36 + quad * 8 + 4);
    bf16x8 paf;
#pragma unroll
    for (int c = 0; c < 4; c++) { paf[c] = (__bf16)plo[c]; paf[c + 4] = (__bf16)phi[c]; }
#pragma unroll
    for (int nc = 0; nc < 19; nc++) {
      f32x4 a = acc[nc];
#pragma unroll
      for (int c = 0; c < 4; c++) a[c] *= al[c];
      acc[nc] = __builtin_amdgcn_mfma_f32_16x16x32_bf16(paf, bufB[nc * 64 + lane], a, 0, 0, 0);
    }
    __syncthreads();  // drains next-chunk DMA + all reads of chunk[cur]
    cur ^= 1;
  }

  size_t prow = (size_t)sl * 4096 + (size_t)b * 128 + w * 16;
  if (n16 == 0) {
#pragma unroll
    for (int r = 0; r < 4; r++) {
      pML[(prow + quad * 4 + r) * 2 + 0] = mrun[r];
      pML[(prow + quad * 4 + r) * 2 + 1] = lrun[r];
    }
  }
#pragma unroll
  for (int nc = 0; nc < 19; nc++)
#pragma unroll
    for (int r = 0; r < 4; r++)
      pAcc[(prow + quad * 4 + r) * 304 + nc * 16 + n16] = f2bf(acc[nc][r]);
}

// ---------- combine slices + default-embed column -> V bf16 (4096 x 320) ----------
__global__ __launch_bounds__(320) void k_combine(
    const u16* __restrict__ pAcc, const float* __restrict__ pML,
    const u16* __restrict__ X, const u16* __restrict__ de,
    const u16* __restrict__ words, u16* __restrict__ Vout) {
  __shared__ float red[320];
  __shared__ float fs[8];
  __shared__ float sinv, sw;
  int row = blockIdx.x, tid = threadIdx.x;
  float p = 0.f;
  if (tid < 300) p = bf2f(X[(size_t)row * 320 + tid]) * bf2f(de[tid]);
  red[tid] = p;
  __syncthreads();
  if (tid == 0) {
    float d = 0.f;
    for (int i = 0; i < 300; i++) d += red[i];
    float mv[8], lv[8], ms = -1e30f;
    for (int s = 0; s < 8; s++) {
      mv[s] = pML[((size_t)s * 4096 + row) * 2];
      lv[s] = pML[((size_t)s * 4096 + row) * 2 + 1];
      ms = fmaxf(ms, mv[s]);
    }
    float mf = fmaxf(ms, d);
    float pd = __expf(d - mf);
    float l = pd;
    for (int s = 0; s < 8; s++) {
      float f = __expf(mv[s] - mf);
      fs[s] = f;
      l += lv[s] * f;
    }
    sinv = 1.f / l;
    sw = pd / l;
  }
  __syncthreads();
  float v = 0.f;
  if (tid < 300) {
    float a = 0.f;
#pragma unroll
    for (int s = 0; s < 8; s++)
      a += bf2f(pAcc[((size_t)s * 4096 + row) * 304 + tid]) * fs[s];
    v = a * sinv + sw * bf2f(words[(size_t)row * 300 + tid]);
  }
  Vout[(size_t)row * 320 + tid] = f2bf(v);
}

// ---------- xg = V @ lstm_Wih.T + bih + bhh (f32, 4096 x 1200) ----------
__global__ __launch_bounds__(256) void k_xg(const u16* __restrict__ Vb,
                                            const u16* __restrict__ WihT,
                                            const u16* __restrict__ bih,
                                            const u16* __restrict__ bhh,
                                            float* __restrict__ xg) {
  __shared__ float As[300][33];
  int n0 = blockIdx.x * 128;
  int r0 = blockIdx.y * 32;
  int tid = threadIdx.x;
  for (int idx = tid; idx < 32 * 300; idx += 256) {
    int r = idx / 300, k = idx - r * 300;
    As[k][r] = bf2f(Vb[(size_t)(r0 + r) * 320 + k]);
  }
  __syncthreads();
  int j = n0 + (tid & 127);
  if (j >= 1200) return;
  int rh = (tid >> 7) * 16;
  float acc[16];
#pragma unroll
  for (int i = 0; i < 16; i++) acc[i] = 0.f;
  for (int k = 0; k < 300; k++) {
    float bw = bf2f(WihT[(size_t)k * 1200 + j]);
#pragma unroll
    for (int i = 0; i < 16; i++) acc[i] += As[k][rh + i] * bw;
  }
  float bias = bf2f(bih[j]) + bf2f(bhh[j]);
#pragma unroll
  for (int i = 0; i < 16; i++)
    xg[(size_t)(r0 + rh + i) * 1200 + j] = acc[i] + bias;
}

// ---------- LSTM: 2 independent cliques x (8 blocks x 16 batches) ----------
// Clique mg handles batches [mg*16, +16); its 8 blocks cover dims in 38-chunks
// (lstm5 pack layout), 10 waves x 16 cols register-resident B-frags (lstm2
// protocol). Per step: acquire-poll 8 clique flags -> 10 A-frag vector loads
// (h for 16 batches) -> 10 MFMA/wave -> gl LDS -> 1 activation item/thread ->
// h publish -> barrier -> release. Cliques never synchronize with each other.
// h buffers: hb[clique][buf][5120 u16] A-layout: ((k>>5)*64+((k>>3)&3)*16+b)*8+(k&7).
__global__ __launch_bounds__(640, 1) void k_lstm7(
    const float* __restrict__ xg, const u16* __restrict__ pW,
    const int* __restrict__ lengths, u16* __restrict__ hb, u32* __restrict__ seq) {
  __shared__ float gl[16][164];
  __shared__ int s_maxlen;
  int bidx = blockIdx.x;
  int mg = bidx >> 3, bid = bidx & 7;
  int tid = threadIdx.x;
  int w = tid >> 6, lane = tid & 63;
  int quad = lane >> 4, n16 = lane & 15;
  int nd = (bid < 7) ? 38 : 34;
  // maxlen over this clique's 16 batches
  {
    int lv = (tid < 16) ? lengths[mg * 16 + tid] : 0;
    for (int off2 = 1; off2 < 16; off2 <<= 1) {
      int o = __shfl_xor(lv, off2, 64);
      lv = lv > o ? lv : o;
    }
    if (tid == 0) s_maxlen = lv;
  }
  // B-frags: constant across steps, register-resident (wave w = N-tile w)
  f16x8 bf[10];
  const u32x4* pw4 = (const u32x4*)(pW + (size_t)bid * 51200);
#pragma unroll
  for (int kt = 0; kt < 10; kt++)
    bf[kt] = __builtin_bit_cast(f16x8, pw4[(w * 10 + kt) * 64 + lane]);
  // activation ownership: 640 threads = 16 batches x 40 dl, 1 item each
  int b0 = tid / 40, dl = tid - b0 * 40;
  bool a0 = dl < nd;
  int bg = mg * 16 + b0;
  int len0 = lengths[bg];
  int dim = 38 * bid + dl;
  int sa = (((dim >> 5)) * 64 + ((dim >> 3) & 3) * 16 + b0) * 8 + (dim & 7);
  float c0 = 0.f, h0 = 0.f;
  u32* myf = seq + (size_t)bidx * 16;
  __syncthreads();
  int maxlen = s_maxlen;
  for (int t = 0; t < maxlen; t++) {
    if (tid < 8) {
      while (__hip_atomic_load(&seq[(mg * 8 + tid) * 16], __ATOMIC_ACQUIRE, SCOPE_AGENT) < (u32)t)
        __builtin_amdgcn_s_sleep(2);
    }
    __syncthreads();
    // xv loads (independent of h; overlap with A-frag latency)
    float xv0 = 0.f, xv1 = 0.f, xv2 = 0.f, xv3 = 0.f;
    const float* xr0 = xg + ((size_t)bg * 128 + t) * 1200 + dim;
    if (a0) { xv0 = xr0[0]; xv1 = xr0[300]; xv2 = xr0[600]; xv3 = xr0[900]; }
    // A-frags: h_{t-1} for this clique's 16 batches, f16 A-layout
    const u32x4* hbt = (const u32x4*)hb + (size_t)(mg * 2 + (t & 1)) * 640;
    u32x4 af[10];
#pragma unroll
    for (int kt = 0; kt < 10; kt++)
      af[kt] = hbt[kt * 64 + lane];
    f32x4 C;
    C[0] = 0.f; C[1] = 0.f; C[2] = 0.f; C[3] = 0.f;
#pragma unroll
    for (int kt = 0; kt < 10; kt++)
      C = __builtin_amdgcn_mfma_f32_16x16x32_f16(
          __builtin_bit_cast(f16x8, af[kt]), bf[kt], C, 0, 0, 0);
#pragma unroll
    for (int rr = 0; rr < 4; rr++)
      gl[quad * 4 + rr][w * 16 + n16] = C[rr];
    __syncthreads();
    u16* hbw = hb + (size_t)(mg * 2 + ((t + 1) & 1)) * 5120;
    if (a0) {
      float gi = gl[b0][dl] + xv0, gf = gl[b0][40 + dl] + xv1;
      float gg = gl[b0][80 + dl] + xv2, go = gl[b0][120 + dl] + xv3;
      if (t < len0) {
        c0 = sigm(gf) * c0 + sigm(gi) * tanhf(gg);
        h0 = sigm(go) * tanhf(c0);
      }
      hbw[sa] = f2h(h0);
    }
    __syncthreads();  // drains vmem stores (vmcnt) block-wide before release
    if (tid == 0)
      __hip_atomic_store(myf, (u32)(t + 1), __ATOMIC_RELEASE, SCOPE_AGENT);
  }
}

// ---------- RNN tail: q from hb (clique A-layout), 8 steps ----------
__global__ __launch_bounds__(320) void k_rnn(
    const u16* __restrict__ hb, const int* __restrict__ lengths,
    const u16* __restrict__ rWihT, const u16* __restrict__ rWhhT,
    const u16* __restrict__ rbih, const u16* __restrict__ rbhh,
    float* __restrict__ H) {
  __shared__ float qs[304], h2[304], base[304];
  __shared__ int s_maxlen;
  int b = blockIdx.x, tid = threadIdx.x;
  int mg = b >> 4;
  {
    int lv = (tid < 16) ? lengths[mg * 16 + tid] : 0;
    for (int off2 = 1; off2 < 16; off2 <<= 1) {
      int o = __shfl_xor(lv, off2, 64);
      lv = lv > o ? lv : o;
    }
    if (tid == 0) s_maxlen = lv;
  }
  __syncthreads();
  int buf = s_maxlen & 1;
  if (tid < 304) {
    float q = 0.f;
    if (tid < 300) {
      int dim = tid;
      int idx = ((dim >> 5) * 64 + ((dim >> 3) & 3) * 16 + (b & 15)) * 8 + (dim & 7);
      q = h2f(hb[(size_t)(mg * 2 + buf) * 5120 + idx]);
    }
    qs[tid] = q;
    h2[tid] = 0.f;
  }
  __syncthreads();
  if (tid < 300) {
    float a = bf2f(rbih[tid]) + bf2f(rbhh[tid]);
    for (int k = 0; k < 300; k++) a += qs[k] * bf2f(rWihT[(size_t)k * 300 + tid]);
    base[tid] = a;
  }
  __syncthreads();
  for (int s = 0; s < 8; s++) {
    float nv = 0.f;
    if (tid < 300) {
      float a = base[tid];
      for (int k = 0; k < 300; k++) a += h2[k] * bf2f(rWhhT[(size_t)k * 300 + tid]);
      nv = tanhf(a);
    }
    __syncthreads();
    if (tid < 300) {
      h2[tid] = nv;
      H[((size_t)b * 8 + s) * 300 + tid] = nv;
    }
    __syncthreads();
  }
}

// ---------- attention readout ----------
__global__ __launch_bounds__(256) void k_attn(const float* __restrict__ H,
                                              const u16* __restrict__ Vb,
                                              const int* __restrict__ lengths,
                                              const u32* __restrict__ flag,
                                              void* __restrict__ dout) {
  __shared__ float Hs[8][304];
  __shared__ float sc[8][128];
  __shared__ float wsum[8];
  int b = blockIdx.x, tid = threadIdx.x;
  int len = lengths[b];
  int is32 = (int)*flag;
  for (int idx = tid; idx < 8 * 300; idx += 256) {
    int k = idx / 300, j = idx - k * 300;
    Hs[k][j] = H[((size_t)b * 8 + k) * 300 + j];
  }
  __syncthreads();
  for (int s = tid; s < len; s += 256) {
    const u16* vr = Vb + (size_t)(b * 128 + s) * 320;
    float a[8];
#pragma unroll
    for (int k = 0; k < 8; k++) a[k] = 0.f;
    for (int j = 0; j < 300; j++) {
      float v = bf2f(vr[j]);
#pragma unroll
      for (int k = 0; k < 8; k++) a[k] += Hs[k][j] * v;
    }
#pragma unroll
    for (int k = 0; k < 8; k++) sc[k][s] = a[k];
  }
  __syncthreads();
  if (tid < 8) {
    float m = -1e30f;
    for (int s = 0; s < len; s++) m = fmaxf(m, sc[tid][s]);
    float l = 0.f;
    for (int s = 0; s < len; s++) { float e = __expf(sc[tid][s] - m); sc[tid][s] = e; l += e; }
    wsum[tid] = 1.f / l;
  }
  __syncthreads();
  int k = tid >> 5, jl = tid & 31;
  for (int j = jl; j < 300; j += 32) {
    float a = 0.f;
    for (int s = 0; s < len; s++) a += sc[k][s] * bf2f(Vb[(size_t)(b * 128 + s) * 320 + j]);
    float val = a * wsum[k];
    size_t o = ((size_t)b * 8 + k) * 300 + j;
    if (is32) ((float*)dout)[o] = val;
    else ((u16*)dout)[o] = f2bf(val);
  }
}

extern "C" void kernel_launch(void* const* d_in, const int* in_sizes, int n_in,
                              void* d_out, int out_size, void* d_ws, size_t ws_size,
                              hipStream_t stream) {
  (void)in_sizes; (void)n_in; (void)out_size; (void)ws_size;
  const void* words = d_in[0];
  const int* lengths = (const int*)d_in[1];
  const void* vocab = d_in[2];
  const void* de = d_in[3];
  const void* W = d_in[4];
  const void* lWih = d_in[5];
  const void* lWhh = d_in[6];
  const void* lbih = d_in[7];
  const void* lbhh = d_in[8];
  const void* rWih = d_in[9];
  const void* rWhh = d_in[10];
  const void* rbih = d_in[11];
  const void* rbhh = d_in[12];

  char* basep = (char*)d_ws;
  size_t off = 0;
  auto take = [&](size_t bytes) -> char* {
    char* p = basep + off;
    off += (bytes + 255) & ~(size_t)255;
    return p;
  };
  u16* cw    = (u16*)take(1228800 * 2);
  u16* cv    = (u16*)take(6000000 * 2);
  u16* cde   = (u16*)take(300 * 2);
  u16* cW    = (u16*)take(90000 * 2);
  u16* cWih  = (u16*)take(360000 * 2);
  u16* cWhh  = (u16*)take(360000 * 2);
  u16* cbih  = (u16*)take(1200 * 2);
  u16* cbhh  = (u16*)take(1200 * 2);
  u16* crWih = (u16*)take(90000 * 2);
  u16* crWhh = (u16*)take(90000 * 2);
  u16* crbih = (u16*)take(300 * 2);
  u16* crbhh = (u16*)take(300 * 2);
  u32* flag  = (u32*)take(256);
  u16*   X     = (u16*)take((size_t)4096 * 320 * 2);
  u16*   Vb    = (u16*)take((size_t)4096 * 320 * 2);
  u16*   WihT  = (u16*)take((size_t)300 * 1200 * 2);
  u16*   pW8   = (u16*)take((size_t)409600 * 2);
  u16*   rWihT = (u16*)take((size_t)300 * 300 * 2);
  u16*   rWhhT = (u16*)take((size_t)300 * 300 * 2);
  u16*   pAcc  = (u16*)take((size_t)8 * 4096 * 304 * 2);
  float* pML   = (float*)take((size_t)8 * 4096 * 2 * 4);
  float* H     = (float*)take((size_t)32 * 8 * 300 * 4);
  u16*   hb    = (u16*)take((size_t)2 * 2 * 5120 * 2);  // [clique][buf][5120]
  u32*   seq   = (u32*)take((size_t)4096 * 4);
  // union region: pA+pB (dead after k_softmax_v), then xg
  char* ureg = take((size_t)25000192);
  u16*   pA = (u16*)ureg;
  u16*   pB = (u16*)(ureg + (size_t)625 * 10240 * 2);
  float* xg = (float*)ureg;

  k_ingest<<<4096, 256, 0, stream>>>(words, vocab, de, W, lWih, lWhh, lbih, lbhh,
                                     rWih, rWhh, rbih, rbhh,
                                     cw, cv, cde, cW, cWih, cWhh, cbih, cbhh,
                                     crWih, crWhh, crbih, crbhh, flag, seq, (u32*)hb);
  k_transpose_bf<<<dim3(38, 10), 256, 0, stream>>>(cWih, WihT, 1200, 300);
  k_transpose_bf<<<dim3(10, 10), 256, 0, stream>>>(crWih, rWihT, 300, 300);
  k_transpose_bf<<<dim3(10, 10), 256, 0, stream>>>(crWhh, rWhhT, 300, 300);
  k_pack_w8<<<1600, 256, 0, stream>>>(cWhh, pW8);
  k_pack_vocab<<<625, 256, 0, stream>>>(cv, pA, pB);
  k_xw<<<dim3(3, 128), 256, 0, stream>>>(cw, cW, X);
  k_softmax_v<<<256, 512, 0, stream>>>(X, pA, pB, pAcc, pML);
  k_combine<<<4096, 320, 0, stream>>>(pAcc, pML, X, cde, cw, Vb);
  k_xg<<<dim3(10, 128), 256, 0, stream>>>(Vb, WihT, cbih, cbhh, xg);
  k_lstm7<<<16, 640, 0, stream>>>(xg, pW8, lengths, hb, seq);
  k_rnn<<<32, 320, 0, stream>>>(hb, lengths, rWihT, rWhhT, crbih, crbhh, H);
  k_attn<<<32, 256, 0, stream>>>(H, Vb, lengths, flag, d_out);
}

// Round 14
// 877.743 us; speedup vs baseline: 2.0260x; 1.1285x over previous
//
#include <hip/hip_runtime.h>

// B=32, S=128, D=300 (pad 320), VOCAB=20000 (625 chunks of 32), K=8.
// Inputs may be f32 or bf16 (runtime-detected); canonicalized to bf16 in ws.

typedef unsigned short u16;
typedef unsigned int   u32;
typedef float  f32x4 __attribute__((ext_vector_type(4)));
typedef u32    u32x4 __attribute__((ext_vector_type(4)));
typedef __bf16 bf16x8 __attribute__((ext_vector_type(8)));
typedef _Float16 f16x2 __attribute__((ext_vector_type(2)));
typedef _Float16 f16x8 __attribute__((ext_vector_type(8)));

#define SCOPE_AGENT __HIP_MEMORY_SCOPE_AGENT

__device__ __forceinline__ float bf2f(u16 u) { return __uint_as_float(((u32)u) << 16); }
__device__ __forceinline__ u16 f2bf(float f) {
  u32 x = __float_as_uint(f);
  u32 r = (x + 0x7fffu + ((x >> 16) & 1u)) >> 16;  // RNE
  return (u16)r;
}
__device__ __forceinline__ float sigm(float x) { return 1.f / (1.f + __expf(-x)); }
__device__ __forceinline__ u16 f2h(float f) {
  union { _Float16 h; u16 u; } cv; cv.h = (_Float16)f; return cv.u;
}
__device__ __forceinline__ float h2f(u16 u) {
  union { _Float16 h; u16 u; } cv; cv.u = u; return (float)cv.h;
}

// DPP lane move (VALU-only cross-lane within 16-lane rows)
template <int CTRL>
__device__ __forceinline__ float dppmv(float v) {
  return __uint_as_float(
      (u32)__builtin_amdgcn_mov_dpp((int)__float_as_uint(v), CTRL, 0xF, 0xF, true));
}

// async global -> LDS stage of one vocab chunk (2496 x 16B)
__device__ __forceinline__ void stage_chunk(const u16* __restrict__ pA,
                                            const u16* __restrict__ pB,
                                            int ci, u16* dst, int tid) {
  const u32x4* gA = (const u32x4*)pA + (size_t)ci * 1280;
  const u32x4* gB = (const u32x4*)pB + (size_t)ci * 1216;
  u32x4* sb = (u32x4*)dst;
#pragma unroll
  for (int i = 0; i < 5; i++) {
    int idx = tid + i * 512;
    if (idx < 2496) {
      const u32x4* g = (idx < 1280) ? (gA + idx) : (gB + (idx - 1280));
      __builtin_amdgcn_global_load_lds(
          (const __attribute__((address_space(1))) u32*)(const u32*)g,
          (__attribute__((address_space(3))) u32*)(u32*)(sb + idx), 16, 0, 0);
    }
  }
}

// ---------- ingest: detect f32 vs bf16, canonicalize all float inputs to bf16 ----------
__device__ __forceinline__ void conv_seg(const void* src, u16* dst, int n, int is32,
                                         int t0, int stride) {
  if (is32) {
    const float* s = (const float*)src;
    for (int i = t0; i < n; i += stride) dst[i] = f2bf(s[i]);
  } else {
    const u16* s = (const u16*)src;
    for (int i = t0; i < n; i += stride) dst[i] = s[i];
  }
}

__global__ __launch_bounds__(256) void k_ingest(
    const void* words, const void* vocab, const void* de, const void* W,
    const void* lWih, const void* lWhh, const void* lbih, const void* lbhh,
    const void* rWih, const void* rWhh, const void* rbih, const void* rbhh,
    u16* cw, u16* cv, u16* cde, u16* cW, u16* cWih, u16* cWhh, u16* cbih, u16* cbhh,
    u16* crWih, u16* crWhh, u16* crbih, u16* crbhh, u32* flag, u32* seqz, u32* hbz) {
  __shared__ int s_is32;
  int tid = threadIdx.x;
  int vote = 0;
  if (tid < 64) {
    u32 w = ((const u32*)words)[tid];
    int e = (w >> 7) & 0xFF;  // bf16 low-element exponent field if bf16-packed
    vote = (e >= 100 && e <= 150) ? 1 : 0;
  }
  unsigned long long m = __ballot(vote);
  if (tid == 0) s_is32 = (__popcll(m) < 32) ? 1 : 0;  // few plausible bf16 exps -> f32
  __syncthreads();
  int is32 = s_is32;
  if (blockIdx.x == 0 && tid == 0) *flag = (u32)is32;
  int t0 = blockIdx.x * 256 + tid;
  int stride = gridDim.x * 256;
  if (t0 < 256) seqz[t0] = 0;     // LSTM step counters (16 flags x stride 16)
  if (t0 < 10240) hbz[t0] = 0;    // LSTM h exchange: 2 cliques x 2 bufs x 5120 u16
  conv_seg(words, cw, 1228800, is32, t0, stride);
  conv_seg(vocab, cv, 6000000, is32, t0, stride);
  conv_seg(de, cde, 300, is32, t0, stride);
  conv_seg(W, cW, 90000, is32, t0, stride);
  conv_seg(lWih, cWih, 360000, is32, t0, stride);
  conv_seg(lWhh, cWhh, 360000, is32, t0, stride);
  conv_seg(lbih, cbih, 1200, is32, t0, stride);
  conv_seg(lbhh, cbhh, 1200, is32, t0, stride);
  conv_seg(rWih, crWih, 90000, is32, t0, stride);
  conv_seg(rWhh, crWhh, 90000, is32, t0, stride);
  conv_seg(rbih, crbih, 300, is32, t0, stride);
  conv_seg(rbhh, crbhh, 300, is32, t0, stride);
}

// ---------- transpose bf16 (J x K) -> bf16 (K x J) ----------
__global__ __launch_bounds__(256) void k_transpose_bf(const u16* __restrict__ in,
                                                      u16* __restrict__ out,
                                                      int J, int K) {
  __shared__ u16 t[32][33];
  int j0 = blockIdx.x * 32, k0 = blockIdx.y * 32;
  int lx = threadIdx.x & 31, ly = threadIdx.x >> 5;
  for (int r = ly; r < 32; r += 8) {
    int j = j0 + r, k = k0 + lx;
    t[r][lx] = (j < J && k < K) ? in[(size_t)j * K + k] : (u16)0;
  }
  __syncthreads();
  for (int r = ly; r < 32; r += 8) {
    int k = k0 + r, j = j0 + lx;
    if (k < K && j < J) out[(size_t)k * J + j] = t[lx][r];
  }
}

// ---------- pack lstm_Whh -> per-dim-block MFMA B-frag slices (f16) ----------
// Block bid owns dims [38*bid, 38*bid+nd) (nd=38, last 34); cols n = gate*40+dl (160).
// Layout: pW[bid*51200 + ((w*10+kt)*64 + lane)*8 + j] f16; wave-tile w = n>>4.
// n = w*16 + (lane&15); gate = n/40; dl = n%40; dim = 38*bid+dl;
// k = kt*32 + (lane>>4)*8 + j; val = Whh[gate*300+dim][k] (0 if dl>=nd or k>=300).
__global__ __launch_bounds__(256) void k_pack_w8(const u16* __restrict__ Whh,
                                                 u16* __restrict__ pW) {
  int idx = blockIdx.x * 256 + threadIdx.x;
  if (idx >= 409600) return;
  int bid = idx / 51200;
  int r = idx - bid * 51200;
  int j = r & 7;
  int lane = (r >> 3) & 63;
  int t2 = r >> 9;           // 0..99 = w*10 + kt
  int kt = t2 % 10, w = t2 / 10;
  int n16 = lane & 15, quad = lane >> 4;
  int n = w * 16 + n16;
  int gate = n / 40, dl = n - gate * 40;
  int nd = (bid < 7) ? 38 : 34;
  int dim = 38 * bid + dl;
  int k = kt * 32 + quad * 8 + j;
  u16 out = 0;
  if (dl < nd && k < 300)
    out = f2h(bf2f(Whh[(size_t)(gate * 300 + dim) * 300 + k]));
  pW[idx] = out;
}

// ---------- pack lstm_Wih (1200x300 bf16) -> MFMA B-frag layout ----------
// pWih[((nc*10 + kt)*64 + lane)*8 + j] bf16; nc=0..74 col-tiles of 16;
// n = nc*16 + (lane&15); k = kt*32 + (lane>>4)*8 + j; val = Wih[n][k] (0 if k>=300).
__global__ __launch_bounds__(256) void k_pack_wih(const u16* __restrict__ cWih,
                                                  u16* __restrict__ pW) {
  int idx = blockIdx.x * 256 + threadIdx.x;
  if (idx >= 384000) return;
  int j = idx & 7;
  int lane = (idx >> 3) & 63;
  int t2 = idx >> 9;         // 0..749 = nc*10 + kt
  int kt = t2 % 10, nc = t2 / 10;
  int n = nc * 16 + (lane & 15);
  int k = kt * 32 + (lane >> 4) * 8 + j;
  pW[idx] = (k < 300) ? cWih[(size_t)n * 300 + k] : (u16)0;
}

// ---------- pack vocab into MFMA operand layouts ----------
__global__ __launch_bounds__(256) void k_pack_vocab(const u16* __restrict__ vocab,
                                                    u16* __restrict__ pA,
                                                    u16* __restrict__ pB) {
  __shared__ u16 sv[32][320];
  int ci = blockIdx.x, tid = threadIdx.x;
  for (int idx = tid; idx < 32 * 20; idx += 256) {
    int v = idx / 20, k = 300 + (idx - v * 20);
    sv[v][k] = 0;
  }
  for (int idx = tid; idx < 32 * 300; idx += 256) {
    int v = idx / 300, k = idx - v * 300;
    sv[v][k] = vocab[(size_t)(ci * 32 + v) * 300 + k];
  }
  __syncthreads();
  for (int idx = tid; idx < 10240; idx += 256) {
    int j = idx & 7, lane = (idx >> 3) & 63, t2 = idx >> 9;
    int kk = t2 % 10, h = t2 / 10;
    int v = h * 16 + (lane & 15);
    int k = kk * 32 + ((lane >> 4)) * 8 + j;
    pA[(size_t)ci * 10240 + (size_t)idx] = sv[v][k];
  }
  for (int idx = tid; idx < 9728; idx += 256) {
    int j = idx & 7, lane = (idx >> 3) & 63, nc = idx >> 9;
    int v = (lane >> 4) * 8 + j;
    int n = nc * 16 + (lane & 15);
    pB[(size_t)ci * 9728 + (size_t)idx] = sv[v][n];
  }
}

// ---------- X = words @ W -> bf16 (4096 x 320, zero pad) ----------
__global__ __launch_bounds__(256) void k_xw(const u16* __restrict__ words,
                                            const u16* __restrict__ W,
                                            u16* __restrict__ X) {
  __shared__ float As[300][33];
  int n0 = blockIdx.x * 128;
  int r0 = blockIdx.y * 32;
  int tid = threadIdx.x;
  for (int idx = tid; idx < 32 * 300; idx += 256) {
    int r = idx / 300, k = idx - r * 300;
    As[k][r] = bf2f(words[(size_t)(r0 + r) * 300 + k]);
  }
  __syncthreads();
  int j = n0 + (tid & 127);
  int rh = (tid >> 7) * 16;
  float acc[16];
#pragma unroll
  for (int i = 0; i < 16; i++) acc[i] = 0.f;
  if (j < 300) {
    for (int k = 0; k < 300; k++) {
      float bw = bf2f(W[(size_t)k * 300 + j]);
#pragma unroll
      for (int i = 0; i < 16; i++) acc[i] += As[k][rh + i] * bw;
    }
  }
  if (j < 320) {
#pragma unroll
    for (int i = 0; i < 16; i++) {
      float v = (j < 300) ? acc[i] : 0.f;
      X[(size_t)(r0 + rh + i) * 320 + j] = f2bf(v);
    }
  }
}

// ---------- flash-style softmax-weighted vocab sum (MFMA), per-slice partials ----------
__global__ __launch_bounds__(512, 2) void k_softmax_v(
    const u16* __restrict__ X, const u16* __restrict__ pA, const u16* __restrict__ pB,
    u16* __restrict__ pAcc, float* __restrict__ pML) {
  __shared__ __align__(16) u16 chunk[2][19968];
  __shared__ __align__(16) float ptbuf[8 * 576];
  int bid = blockIdx.x;
  int sl = bid & 7, b = bid >> 3;
  int tid = threadIdx.x;
  int w = tid >> 6, lane = tid & 63;
  int quad = lane >> 4, n16 = lane & 15;
  int cs = (sl == 0) ? 0 : 79 + (sl - 1) * 78;
  int nch = (sl == 0) ? 79 : 78;

  int rowA = b * 128 + w * 16 + n16;
  const bf16x8* Xrow = (const bf16x8*)(X + (size_t)rowA * 320);
  bf16x8 afr[10];
#pragma unroll
  for (int kk = 0; kk < 10; kk++) afr[kk] = Xrow[kk * 4 + quad];

  f32x4 acc[19];
#pragma unroll
  for (int i = 0; i < 19; i++) { acc[i][0] = 0.f; acc[i][1] = 0.f; acc[i][2] = 0.f; acc[i][3] = 0.f; }
  f32x4 mrun, lrun;
#pragma unroll
  for (int c = 0; c < 4; c++) { mrun[c] = -1e30f; lrun[c] = 0.f; }
  float* myPt = ptbuf + w * 576;

  stage_chunk(pA, pB, cs, &chunk[0][0], tid);
  __syncthreads();  // barrier implies vmcnt(0): DMA complete

  int cur = 0;
  for (int ic = 0; ic < nch; ic++) {
    if (ic + 1 < nch) stage_chunk(pA, pB, cs + ic + 1, &chunk[cur ^ 1][0], tid);
    const bf16x8* bufA = (const bf16x8*)&chunk[cur][0];
    const bf16x8* bufB = (const bf16x8*)&chunk[cur][10240];
    f32x4 L0, L1;
#pragma unroll
    for (int c = 0; c < 4; c++) { L0[c] = 0.f; L1[c] = 0.f; }
#pragma unroll
    for (int kk = 0; kk < 10; kk++) {
      L0 = __builtin_amdgcn_mfma_f32_16x16x32_bf16(afr[kk], bufA[kk * 64 + lane], L0, 0, 0, 0);
      L1 = __builtin_amdgcn_mfma_f32_16x16x32_bf16(afr[kk], bufA[(10 + kk) * 64 + lane], L1, 0, 0, 0);
    }
    f32x4 t;
#pragma unroll
    for (int c = 0; c < 4; c++) {
      float x = fmaxf(L0[c], L1[c]);
      x = fmaxf(x, dppmv<0xB1>(x));
      x = fmaxf(x, dppmv<0x4E>(x));
      x = fmaxf(x, dppmv<0x141>(x));
      x = fmaxf(x, dppmv<0x140>(x));
      t[c] = x;
    }
    f32x4 mnew, al, P0v, P1v, rs;
#pragma unroll
    for (int c = 0; c < 4; c++) {
      mnew[c] = fmaxf(mrun[c], t[c]);
      al[c] = __expf(mrun[c] - mnew[c]);
      P0v[c] = __expf(L0[c] - mnew[c]);
      P1v[c] = __expf(L1[c] - mnew[c]);
      rs[c] = P0v[c] + P1v[c];
    }
#pragma unroll
    for (int c = 0; c < 4; c++) {
      float x = rs[c];
      x += dppmv<0xB1>(x);
      x += dppmv<0x4E>(x);
      x += dppmv<0x141>(x);
      x += dppmv<0x140>(x);
      rs[c] = x;
    }
#pragma unroll
    for (int c = 0; c < 4; c++) { lrun[c] = lrun[c] * al[c] + rs[c]; mrun[c] = mnew[c]; }
#pragma unroll
    for (int r = 0; r < 4; r++) {
      myPt[(quad * 4 + r) * 36 + n16] = P0v[r];
      myPt[(quad * 4 + r) * 36 + 16 + n16] = P1v[r];
    }
    f32x4 plo = *(const f32x4*)(myPt + n16 * 36 + quad * 8);
    f32x4 phi = *(const f32x4*)(myPt + n16 * 36 + quad * 8 + 4);
    bf16x8 paf;
#pragma unroll
    for (int c = 0; c < 4; c++) { paf[c] = (__bf16)plo[c]; paf[c + 4] = (__bf16)phi[c]; }
#pragma unroll
    for (int nc = 0; nc < 19; nc++) {
      f32x4 a = acc[nc];
#pragma unroll
      for (int c = 0; c < 4; c++) a[c] *= al[c];
      acc[nc] = __builtin_amdgcn_mfma_f32_16x16x32_bf16(paf, bufB[nc * 64 + lane], a, 0, 0, 0);
    }
    __syncthreads();  // drains next-chunk DMA + all reads of chunk[cur]
    cur ^= 1;
  }

  size_t prow = (size_t)sl * 4096 + (size_t)b * 128 + w * 16;
  if (n16 == 0) {
#pragma unroll
    for (int r = 0; r < 4; r++) {
      pML[(prow + quad * 4 + r) * 2 + 0] = mrun[r];
      pML[(prow + quad * 4 + r) * 2 + 1] = lrun[r];
    }
  }
#pragma unroll
  for (int nc = 0; nc < 19; nc++)
#pragma unroll
    for (int r = 0; r < 4; r++)
      pAcc[(prow + quad * 4 + r) * 304 + nc * 16 + n16] = f2bf(acc[nc][r]);
}

// ---------- combine slices + default-embed column -> V bf16 (4096 x 320) ----------
__global__ __launch_bounds__(320) void k_combine(
    const u16* __restrict__ pAcc, const float* __restrict__ pML,
    const u16* __restrict__ X, const u16* __restrict__ de,
    const u16* __restrict__ words, u16* __restrict__ Vout) {
  __shared__ float red[320];
  __shared__ float fs[8];
  __shared__ float sinv, sw;
  int row = blockIdx.x, tid = threadIdx.x;
  float p = 0.f;
  if (tid < 300) p = bf2f(X[(size_t)row * 320 + tid]) * bf2f(de[tid]);
  red[tid] = p;
  __syncthreads();
  // wave-parallel 320-sum (red[300..319] are zero)
  if (tid < 64) {
    float s = red[tid] + red[tid + 64] + red[tid + 128] + red[tid + 192] + red[tid + 256];
    for (int off = 32; off; off >>= 1) s += __shfl_xor(s, off, 64);
    if (tid == 0) red[0] = s;
  }
  __syncthreads();
  if (tid == 0) {
    float d = red[0];
    float mv[8], lv[8], ms = -1e30f;
    for (int s = 0; s < 8; s++) {
      mv[s] = pML[((size_t)s * 4096 + row) * 2];
      lv[s] = pML[((size_t)s * 4096 + row) * 2 + 1];
      ms = fmaxf(ms, mv[s]);
    }
    float mf = fmaxf(ms, d);
    float pd = __expf(d - mf);
    float l = pd;
    for (int s = 0; s < 8; s++) {
      float f = __expf(mv[s] - mf);
      fs[s] = f;
      l += lv[s] * f;
    }
    sinv = 1.f / l;
    sw = pd / l;
  }
  __syncthreads();
  float v = 0.f;
  if (tid < 300) {
    float a = 0.f;
#pragma unroll
    for (int s = 0; s < 8; s++)
      a += bf2f(pAcc[((size_t)s * 4096 + row) * 304 + tid]) * fs[s];
    v = a * sinv + sw * bf2f(words[(size_t)row * 300 + tid]);
  }
  Vout[(size_t)row * 320 + tid] = f2bf(v);
}

// ---------- xg = V @ lstm_Wih.T + bih + bhh -> f32 (4096 x 1200), MFMA bf16 ----------
// Grid (5 col-blocks x 64 row-blocks), 256 thr = 4 waves x 16 rows. Wave loops
// 15 col-tiles of 16; A-frags from padded Vb rows (zero cols 300..319), B-frags
// from pWih pack (zero k>=300). C/D: col=lane&15, row=(lane>>4)*4+reg.
__global__ __launch_bounds__(256) void k_xg(const u16* __restrict__ Vb,
                                            const u16* __restrict__ pWih,
                                            const u16* __restrict__ bih,
                                            const u16* __restrict__ bhh,
                                            float* __restrict__ xg) {
  int cb = blockIdx.x;   // 0..4: cols [cb*240, +240)
  int rb = blockIdx.y;   // 0..63: rows [rb*64, +64)
  int tid = threadIdx.x;
  int w = tid >> 6, lane = tid & 63;
  int quad = lane >> 4, n16 = lane & 15;
  int rowA = rb * 64 + w * 16 + n16;
  const bf16x8* Xrow = (const bf16x8*)(Vb + (size_t)rowA * 320);
  bf16x8 afr[10];
#pragma unroll
  for (int kt = 0; kt < 10; kt++) afr[kt] = Xrow[kt * 4 + quad];
  const u32x4* pw4 = (const u32x4*)pWih;
  int rb4 = rb * 64 + w * 16 + quad * 4;
  for (int nc2 = 0; nc2 < 15; nc2++) {
    int nc = cb * 15 + nc2;
    f32x4 C;
    C[0] = 0.f; C[1] = 0.f; C[2] = 0.f; C[3] = 0.f;
#pragma unroll
    for (int kt = 0; kt < 10; kt++)
      C = __builtin_amdgcn_mfma_f32_16x16x32_bf16(
          afr[kt], __builtin_bit_cast(bf16x8, pw4[(nc * 10 + kt) * 64 + lane]), C, 0, 0, 0);
    int n = nc * 16 + n16;
    float bias = bf2f(bih[n]) + bf2f(bhh[n]);
#pragma unroll
    for (int r = 0; r < 4; r++)
      xg[(size_t)(rb4 + r) * 1200 + n] = C[r] + bias;
  }
}

// ---------- LSTM: 2 independent cliques x (8 blocks x 16 batches) ----------
// Clique mg handles batches [mg*16, +16); its 8 blocks cover dims in 38-chunks
// (lstm5 pack layout), 10 waves x 16 cols register-resident B-frags (lstm2
// protocol). Per step: acquire-poll 8 clique flags -> 10 A-frag vector loads
// (h for 16 batches) -> 10 MFMA/wave -> gl LDS -> 1 activation item/thread ->
// h publish -> barrier -> release. Cliques never synchronize with each other.
// h buffers: hb[clique][buf][5120 u16] A-layout: ((k>>5)*64+((k>>3)&3)*16+b)*8+(k&7).
__global__ __launch_bounds__(640, 1) void k_lstm7(
    const float* __restrict__ xg, const u16* __restrict__ pW,
    const int* __restrict__ lengths, u16* __restrict__ hb, u32* __restrict__ seq) {
  __shared__ float gl[16][164];
  __shared__ int s_maxlen;
  int bidx = blockIdx.x;
  int mg = bidx >> 3, bid = bidx & 7;
  int tid = threadIdx.x;
  int w = tid >> 6, lane = tid & 63;
  int quad = lane >> 4, n16 = lane & 15;
  int nd = (bid < 7) ? 38 : 34;
  // maxlen over this clique's 16 batches
  {
    int lv = (tid < 16) ? lengths[mg * 16 + tid] : 0;
    for (int off2 = 1; off2 < 16; off2 <<= 1) {
      int o = __shfl_xor(lv, off2, 64);
      lv = lv > o ? lv : o;
    }
    if (tid == 0) s_maxlen = lv;
  }
  // B-frags: constant across steps, register-resident (wave w = N-tile w)
  f16x8 bf[10];
  const u32x4* pw4 = (const u32x4*)(pW + (size_t)bid * 51200);
#pragma unroll
  for (int kt = 0; kt < 10; kt++)
    bf[kt] = __builtin_bit_cast(f16x8, pw4[(w * 10 + kt) * 64 + lane]);
  // activation ownership: 640 threads = 16 batches x 40 dl, 1 item each
  int b0 = tid / 40, dl = tid - b0 * 40;
  bool a0 = dl < nd;
  int bg = mg * 16 + b0;
  int len0 = lengths[bg];
  int dim = 38 * bid + dl;
  int sa = (((dim >> 5)) * 64 + ((dim >> 3) & 3) * 16 + b0) * 8 + (dim & 7);
  float c0 = 0.f, h0 = 0.f;
  u32* myf = seq + (size_t)bidx * 16;
  __syncthreads();
  int maxlen = s_maxlen;
  for (int t = 0; t < maxlen; t++) {
    if (tid < 8) {
      while (__hip_atomic_load(&seq[(mg * 8 + tid) * 16], __ATOMIC_ACQUIRE, SCOPE_AGENT) < (u32)t)
        __builtin_amdgcn_s_sleep(2);
    }
    __syncthreads();
    // xv loads (independent of h; overlap with A-frag latency)
    float xv0 = 0.f, xv1 = 0.f, xv2 = 0.f, xv3 = 0.f;
    const float* xr0 = xg + ((size_t)bg * 128 + t) * 1200 + dim;
    if (a0) { xv0 = xr0[0]; xv1 = xr0[300]; xv2 = xr0[600]; xv3 = xr0[900]; }
    // A-frags: h_{t-1} for this clique's 16 batches, f16 A-layout
    const u32x4* hbt = (const u32x4*)hb + (size_t)(mg * 2 + (t & 1)) * 640;
    u32x4 af[10];
#pragma unroll
    for (int kt = 0; kt < 10; kt++)
      af[kt] = hbt[kt * 64 + lane];
    f32x4 C;
    C[0] = 0.f; C[1] = 0.f; C[2] = 0.f; C[3] = 0.f;
#pragma unroll
    for (int kt = 0; kt < 10; kt++)
      C = __builtin_amdgcn_mfma_f32_16x16x32_f16(
          __builtin_bit_cast(f16x8, af[kt]), bf[kt], C, 0, 0, 0);
#pragma unroll
    for (int rr = 0; rr < 4; rr++)
      gl[quad * 4 + rr][w * 16 + n16] = C[rr];
    __syncthreads();
    u16* hbw = hb + (size_t)(mg * 2 + ((t + 1) & 1)) * 5120;
    if (a0) {
      float gi = gl[b0][dl] + xv0, gf = gl[b0][40 + dl] + xv1;
      float gg = gl[b0][80 + dl] + xv2, go = gl[b0][120 + dl] + xv3;
      if (t < len0) {
        c0 = sigm(gf) * c0 + sigm(gi) * tanhf(gg);
        h0 = sigm(go) * tanhf(c0);
      }
      hbw[sa] = f2h(h0);
    }
    __syncthreads();  // drains vmem stores (vmcnt) block-wide before release
    if (tid == 0)
      __hip_atomic_store(myf, (u32)(t + 1), __ATOMIC_RELEASE, SCOPE_AGENT);
  }
}

// ---------- RNN tail: q from hb (clique A-layout), 8 steps ----------
__global__ __launch_bounds__(320) void k_rnn(
    const u16* __restrict__ hb, const int* __restrict__ lengths,
    const u16* __restrict__ rWihT, const u16* __restrict__ rWhhT,
    const u16* __restrict__ rbih, const u16* __restrict__ rbhh,
    float* __restrict__ H) {
  __shared__ float qs[304], h2[304], base[304];
  __shared__ int s_maxlen;
  int b = blockIdx.x, tid = threadIdx.x;
  int mg = b >> 4;
  {
    int lv = (tid < 16) ? lengths[mg * 16 + tid] : 0;
    for (int off2 = 1; off2 < 16; off2 <<= 1) {
      int o = __shfl_xor(lv, off2, 64);
      lv = lv > o ? lv : o;
    }
    if (tid == 0) s_maxlen = lv;
  }
  __syncthreads();
  int buf = s_maxlen & 1;
  if (tid < 304) {
    float q = 0.f;
    if (tid < 300) {
      int dim = tid;
      int idx = ((dim >> 5) * 64 + ((dim >> 3) & 3) * 16 + (b & 15)) * 8 + (dim & 7);
      q = h2f(hb[(size_t)(mg * 2 + buf) * 5120 + idx]);
    }
    qs[tid] = q;
    h2[tid] = 0.f;
  }
  __syncthreads();
  if (tid < 300) {
    float a = bf2f(rbih[tid]) + bf2f(rbhh[tid]);
    for (int k = 0; k < 300; k++) a += qs[k] * bf2f(rWihT[(size_t)k * 300 + tid]);
    base[tid] = a;
  }
  __syncthreads();
  for (int s = 0; s < 8; s++) {
    float nv = 0.f;
    if (tid < 300) {
      float a = base[tid];
      for (int k = 0; k < 300; k++) a += h2[k] * bf2f(rWhhT[(size_t)k * 300 + tid]);
      nv = tanhf(a);
    }
    __syncthreads();
    if (tid < 300) {
      h2[tid] = nv;
      H[((size_t)b * 8 + s) * 300 + tid] = nv;
    }
    __syncthreads();
  }
}

// ---------- attention readout: 256 blocks = (b, k) pairs ----------
__global__ __launch_bounds__(256) void k_attn(const float* __restrict__ H,
                                              const u16* __restrict__ Vb,
                                              const int* __restrict__ lengths,
                                              const u32* __restrict__ flag,
                                              void* __restrict__ dout) {
  __shared__ float Hs[304];
  __shared__ float sc[128];
  __shared__ float winv;
  int bid = blockIdx.x;
  int b = bid >> 3, k = bid & 7;
  int tid = threadIdx.x;
  int len = lengths[b];  // >= 64 by construction (S//2..S)
  int is32 = (int)*flag;
  for (int j = tid; j < 300; j += 256) Hs[j] = H[((size_t)b * 8 + k) * 300 + j];
  __syncthreads();
  for (int s = tid; s < len; s += 256) {
    const u16* vr = Vb + (size_t)(b * 128 + s) * 320;
    float a = 0.f;
    for (int j = 0; j < 300; j++) a += Hs[j] * bf2f(vr[j]);
    sc[s] = a;
  }
  __syncthreads();
  if (tid < 64) {
    float m = sc[tid];  // len >= 64
    if (tid + 64 < len) m = fmaxf(m, sc[tid + 64]);
    for (int off = 32; off; off >>= 1) m = fmaxf(m, __shfl_xor(m, off, 64));
    float e0 = __expf(sc[tid] - m);
    sc[tid] = e0;
    float e1 = 0.f;
    if (tid + 64 < len) { e1 = __expf(sc[tid + 64] - m); sc[tid + 64] = e1; }
    float l = e0 + e1;
    for (int off = 32; off; off >>= 1) l += __shfl_xor(l, off, 64);
    if (tid == 0) winv = 1.f / l;
  }
  __syncthreads();
  float ws = winv;
  for (int j = tid; j < 300; j += 256) {
    float a = 0.f;
    for (int s = 0; s < len; s++) a += sc[s] * bf2f(Vb[(size_t)(b * 128 + s) * 320 + j]);
    float val = a * ws;
    size_t o = ((size_t)b * 8 + k) * 300 + j;
    if (is32) ((float*)dout)[o] = val;
    else ((u16*)dout)[o] = f2bf(val);
  }
}

extern "C" void kernel_launch(void* const* d_in, const int* in_sizes, int n_in,
                              void* d_out, int out_size, void* d_ws, size_t ws_size,
                              hipStream_t stream) {
  (void)in_sizes; (void)n_in; (void)out_size; (void)ws_size;
  const void* words = d_in[0];
  const int* lengths = (const int*)d_in[1];
  const void* vocab = d_in[2];
  const void* de = d_in[3];
  const void* W = d_in[4];
  const void* lWih = d_in[5];
  const void* lWhh = d_in[6];
  const void* lbih = d_in[7];
  const void* lbhh = d_in[8];
  const void* rWih = d_in[9];
  const void* rWhh = d_in[10];
  const void* rbih = d_in[11];
  const void* rbhh = d_in[12];

  char* basep = (char*)d_ws;
  size_t off = 0;
  auto take = [&](size_t bytes) -> char* {
    char* p = basep + off;
    off += (bytes + 255) & ~(size_t)255;
    return p;
  };
  u16* cw    = (u16*)take(1228800 * 2);
  u16* cv    = (u16*)take(6000000 * 2);
  u16* cde   = (u16*)take(300 * 2);
  u16* cW    = (u16*)take(90000 * 2);
  u16* cWih  = (u16*)take(360000 * 2);
  u16* cWhh  = (u16*)take(360000 * 2);
  u16* cbih  = (u16*)take(1200 * 2);
  u16* cbhh  = (u16*)take(1200 * 2);
  u16* crWih = (u16*)take(90000 * 2);
  u16* crWhh = (u16*)take(90000 * 2);
  u16* crbih = (u16*)take(300 * 2);
  u16* crbhh = (u16*)take(300 * 2);
  u32* flag  = (u32*)take(256);
  u16*   X     = (u16*)take((size_t)4096 * 320 * 2);
  u16*   Vb    = (u16*)take((size_t)4096 * 320 * 2);
  u16*   pWih  = (u16*)take((size_t)384000 * 2);
  u16*   pW8   = (u16*)take((size_t)409600 * 2);
  u16*   rWihT = (u16*)take((size_t)300 * 300 * 2);
  u16*   rWhhT = (u16*)take((size_t)300 * 300 * 2);
  u16*   pAcc  = (u16*)take((size_t)8 * 4096 * 304 * 2);
  float* pML   = (float*)take((size_t)8 * 4096 * 2 * 4);
  float* H     = (float*)take((size_t)32 * 8 * 300 * 4);
  u16*   hb    = (u16*)take((size_t)2 * 2 * 5120 * 2);  // [clique][buf][5120]
  u32*   seq   = (u32*)take((size_t)4096 * 4);
  // union region: pA+pB (dead after k_softmax_v), then xg
  char* ureg = take((size_t)25000192);
  u16*   pA = (u16*)ureg;
  u16*   pB = (u16*)(ureg + (size_t)625 * 10240 * 2);
  float* xg = (float*)ureg;

  k_ingest<<<4096, 256, 0, stream>>>(words, vocab, de, W, lWih, lWhh, lbih, lbhh,
                                     rWih, rWhh, rbih, rbhh,
                                     cw, cv, cde, cW, cWih, cWhh, cbih, cbhh,
                                     crWih, crWhh, crbih, crbhh, flag, seq, (u32*)hb);
  k_pack_wih<<<1500, 256, 0, stream>>>(cWih, pWih);
  k_transpose_bf<<<dim3(10, 10), 256, 0, stream>>>(crWih, rWihT, 300, 300);
  k_transpose_bf<<<dim3(10, 10), 256, 0, stream>>>(crWhh, rWhhT, 300, 300);
  k_pack_w8<<<1600, 256, 0, stream>>>(cWhh, pW8);
  k_pack_vocab<<<625, 256, 0, stream>>>(cv, pA, pB);
  k_xw<<<dim3(3, 128), 256, 0, stream>>>(cw, cW, X);
  k_softmax_v<<<256, 512, 0, stream>>>(X, pA, pB, pAcc, pML);
  k_combine<<<4096, 320, 0, stream>>>(pAcc, pML, X, cde, cw, Vb);
  k_xg<<<dim3(5, 64), 256, 0, stream>>>(Vb, pWih, cbih, cbhh, xg);
  k_lstm7<<<16, 640, 0, stream>>>(xg, pW8, lengths, hb, seq);
  k_rnn<<<32, 320, 0, stream>>>(hb, lengths, rWihT, rWhhT, crbih, crbhh, H);
  k_attn<<<256, 256, 0, stream>>>(H, Vb, lengths, flag, d_out);
}